// Round 1
// baseline (4206.155 us; speedup 1.0000x reference)
//
#include <hip/hip_runtime.h>
#include <math.h>

#define N_NODES 100000
#define N_PREV  80000
#define N_EDGES 1000000
#define DIM     128
#define BATCH   8
#define KTOT    1664   // 13*128

// ---- ordered-uint encoding for float atomic max/min ----
__device__ __forceinline__ unsigned enc_f(float f) {
    unsigned u = __float_as_uint(f);
    return (u & 0x80000000u) ? ~u : (u | 0x80000000u);
}
__device__ __forceinline__ float dec_f(unsigned u) {
    u = (u & 0x80000000u) ? (u & 0x7FFFFFFFu) : ~u;
    return __uint_as_float(u);
}

__global__ void k_init(float* __restrict__ sum, float* __restrict__ sumsq,
                       unsigned* __restrict__ maxe, unsigned* __restrict__ mine,
                       float* __restrict__ deg, int* __restrict__ inv,
                       int* __restrict__ user_idx) {
    int i = blockIdx.x * blockDim.x + threadIdx.x;
    if (i < N_NODES * DIM) {
        sum[i] = 0.f; sumsq[i] = 0.f;
        maxe[i] = 0x007FFFFFu;   // enc(-inf)
        mine[i] = 0xFF800000u;   // enc(+inf)
    }
    if (i < N_NODES) { deg[i] = 0.f; inv[i] = -1; }
    if (i < BATCH) user_idx[i] = 0x7FFFFFFF;
}

__global__ void k_scatter(const int* __restrict__ old_idx, const int* __restrict__ nodes,
                          const int* __restrict__ q_sub, int* __restrict__ inv,
                          int* __restrict__ user_idx) {
    int i = blockIdx.x * blockDim.x + threadIdx.x;
    if (i < N_PREV) inv[old_idx[i]] = i;
    if (i < N_NODES) {
        int b = nodes[2 * i], e = nodes[2 * i + 1];
        if (b >= 0 && b < BATCH && q_sub[b] == e) atomicMin(&user_idx[b], i);
    }
}

// one wave (64 lanes) per edge; lane handles elems 2*lane, 2*lane+1
__global__ __launch_bounds__(256) void k_edges(
    const float* __restrict__ hidden, const float* __restrict__ rela,
    const int* __restrict__ edges,
    float* __restrict__ sum, float* __restrict__ sumsq,
    unsigned* __restrict__ maxe, unsigned* __restrict__ mine,
    float* __restrict__ deg)
{
    int wid = (blockIdx.x * blockDim.x + threadIdx.x) >> 6;
    int lane = threadIdx.x & 63;
    if (wid >= N_EDGES) return;
    int sub = edges[wid * 6 + 4];
    int rel = edges[wid * 6 + 2];
    int obj = edges[wid * 6 + 5];

    float2 u = *(const float2*)&hidden[sub * DIM + lane * 2];
    float2 r = *(const float2*)&rela[rel * DIM + lane * 2];

    float ps = u.x * u.x + u.y * u.y;
    float pr = r.x * r.x + r.y * r.y;
    float pc = u.x * r.x + u.y * r.y;
#pragma unroll
    for (int off = 32; off; off >>= 1) {
        ps += __shfl_xor(ps, off);
        pr += __shfl_xor(pr, off);
        pc += __shfl_xor(pc, off);
    }
    const float MAXN = 0.996f;  // (1-EPS_BALL)/sqrt(C)
    // expmap0 + project, analytic norms
    float ns = fmaxf(sqrtf(ps), 1e-15f);
    float ts = tanhf(fminf(ns, 15.f));
    float cs = fminf(ts, MAXN);
    float sx = cs / ns;          // x = hs * sx, ||x|| = cs
    float x2 = cs * cs;
    float nr = fmaxf(sqrtf(pr), 1e-15f);
    float tr = tanhf(fminf(nr, 15.f));
    float cr = fminf(tr, MAXN);
    float sy = cr / nr;
    float y2 = cr * cr;
    // mobius_add
    float xy  = pc * sx * sy;
    float ca  = 1.f + 2.f * xy + y2;
    float cb  = 1.f - x2;
    float den = fmaxf(1.f + 2.f * xy + x2 * y2, 1e-15f);
    float id  = 1.f / den;
    float m0 = (ca * (u.x * sx) + cb * (r.x * sy)) * id;
    float m1 = (ca * (u.y * sx) + cb * (r.y * sy)) * id;
    float pm = m0 * m0 + m1 * m1;
#pragma unroll
    for (int off = 32; off; off >>= 1) pm += __shfl_xor(pm, off);
    // project + logmap0:  msg = m * atanh(min(||m||,0.996)) / ||m||
    float nm = fmaxf(sqrtf(pm), 1e-15f);
    float ny = fminf(nm, MAXN);
    float a  = atanhf(ny);
    float sc = a / nm;
    float g0 = m0 * sc, g1 = m1 * sc;

    int base = obj * DIM + lane * 2;
    atomicAdd(&sum[base],     g0);
    atomicAdd(&sum[base + 1], g1);
    atomicAdd(&sumsq[base],     g0 * g0);
    atomicAdd(&sumsq[base + 1], g1 * g1);
    atomicMax(&maxe[base],     enc_f(g0));
    atomicMax(&maxe[base + 1], enc_f(g1));
    atomicMin(&mine[base],     enc_f(g0));
    atomicMin(&mine[base + 1], enc_f(g1));
    if (lane == 0) atomicAdd(&deg[obj], 1.f);
}

// finalize in place: sum<-mean, sumsq<-std, maxe<-mx(float), mine<-mn(float)
__global__ void k_finalize(float* __restrict__ sum, float* __restrict__ sumsq,
                           unsigned* __restrict__ maxe, unsigned* __restrict__ mine,
                           const float* __restrict__ deg,
                           float* __restrict__ amp, float* __restrict__ att) {
    int i = blockIdx.x * blockDim.x + threadIdx.x;
    if (i >= N_NODES * DIM) return;
    int n = i >> 7;
    float d  = deg[n];
    float d1 = fmaxf(d, 1.f);
    float mean = sum[i] / d1;
    float m2   = sumsq[i] / d1;
    float sd = sqrtf(fmaxf(m2 - mean * mean, 0.f) + 1e-10f);
    bool has = d > 0.f;
    float mx = has ? dec_f(maxe[i]) : 0.f;
    float mn = has ? dec_f(mine[i]) : 0.f;
    sum[i] = mean;
    sumsq[i] = sd;
    ((float*)maxe)[i] = mx;
    ((float*)mine)[i] = mn;
    if ((i & 127) == 0) {
        float logd = log1pf(d);
        amp[n] = logd;                      // logd / PNA_DELTA
        att[n] = 1.f / fmaxf(logd, 1e-5f);  // PNA_DELTA / max(logd,1e-5)
    }
}

// h_tilde = feat @ W_agg + b_agg   (M=100000, K=1664, N=128), f32 VALU
#define BM 64
#define BK 32
__global__ __launch_bounds__(256) void k_gemm(
    const float* __restrict__ mean_, const float* __restrict__ mx_,
    const float* __restrict__ mn_, const float* __restrict__ sd_,
    const float* __restrict__ amp, const float* __restrict__ att,
    const int* __restrict__ inv, const float* __restrict__ hidden,
    const float* __restrict__ W, const float* __restrict__ b,
    float* __restrict__ out)
{
    __shared__ float As[BM][BK + 1];   // [64][33]
    __shared__ float Ws[BK][DIM];      // [32][128]
    int tid = threadIdx.x;
    int n0 = blockIdx.x * BM;
    int tm = tid >> 4;   // 0..15 -> 4 nodes each
    int tn = tid & 15;   // 0..15 -> 8 outputs each
    float acc[4][8];
#pragma unroll
    for (int q = 0; q < 4; q++)
#pragma unroll
        for (int rr = 0; rr < 8; rr++) acc[q][rr] = 0.f;

    const float* bufs[4] = {mean_, mx_, mn_, sd_};

    for (int k0 = 0; k0 < KTOT; k0 += BK) {
        // A tile: 64 nodes x 32 k, k-minor for coalescing
#pragma unroll
        for (int i = 0; i < 8; i++) {
            int idx = tid + i * 256;
            int m  = idx >> 5;
            int kk = idx & 31;
            int n = n0 + m; if (n >= N_NODES) n = N_NODES - 1;
            int kg = k0 + kk;
            float v;
            if (kg < 1536) {
                int seg = kg >> 9;       // 0:agg 1:agg*amp 2:agg*att
                int j = kg & 511;
                v = bufs[j >> 7][n * DIM + (j & 127)];
                if (seg == 1) v *= amp[n];
                else if (seg == 2) v *= att[n];
            } else {
                int ii = inv[n];
                v = (ii >= 0) ? hidden[ii * DIM + (kg - 1536)] : 0.f;
            }
            As[m][kk] = v;
        }
        // W tile: 32 x 128, float4
#pragma unroll
        for (int i = 0; i < 4; i++) {
            int idx = tid + i * 256;
            int kk = idx >> 5;
            int j4 = idx & 31;
            *(float4*)&Ws[kk][j4 * 4] = *(const float4*)&W[(size_t)(k0 + kk) * DIM + j4 * 4];
        }
        __syncthreads();
#pragma unroll
        for (int kk = 0; kk < BK; kk++) {
            float a[4];
#pragma unroll
            for (int q = 0; q < 4; q++) a[q] = As[tm * 4 + q][kk];
            float4 w0 = *(float4*)&Ws[kk][tn * 8];
            float4 w1 = *(float4*)&Ws[kk][tn * 8 + 4];
            float w[8] = {w0.x, w0.y, w0.z, w0.w, w1.x, w1.y, w1.z, w1.w};
#pragma unroll
            for (int q = 0; q < 4; q++)
#pragma unroll
                for (int rr = 0; rr < 8; rr++) acc[q][rr] += a[q] * w[rr];
        }
        __syncthreads();
    }
#pragma unroll
    for (int q = 0; q < 4; q++) {
        int n = n0 + tm * 4 + q;
        if (n < N_NODES) {
            float4 o0 = make_float4(acc[q][0] + b[tn * 8 + 0], acc[q][1] + b[tn * 8 + 1],
                                    acc[q][2] + b[tn * 8 + 2], acc[q][3] + b[tn * 8 + 3]);
            float4 o1 = make_float4(acc[q][4] + b[tn * 8 + 4], acc[q][5] + b[tn * 8 + 5],
                                    acc[q][6] + b[tn * 8 + 6], acc[q][7] + b[tn * 8 + 7]);
            *(float4*)&out[(size_t)n * DIM + tn * 8] = o0;
            *(float4*)&out[(size_t)n * DIM + tn * 8 + 4] = o1;
        }
    }
}

__global__ void k_user(const int* __restrict__ user_idx, const float* __restrict__ htilde,
                       float* __restrict__ h_user) {
    int t = blockIdx.x * blockDim.x + threadIdx.x;
    if (t < BATCH * DIM) {
        int b = t >> 7, d = t & 127;
        int idx = user_idx[b];
        if (idx == 0x7FFFFFFF) idx = 0;   // argmax of all-False -> 0
        h_user[t] = htilde[(size_t)idx * DIM + d];
    }
}

// wave per node: alpha = sigmoid(pair @ W_score + b); out = alpha * h_tilde (in place)
__global__ __launch_bounds__(256) void k_score(
    const float* __restrict__ h_user, const int* __restrict__ nodes,
    const float* __restrict__ Wsc, const float* __restrict__ bsc,
    float* __restrict__ out)
{
    int wid = (blockIdx.x * blockDim.x + threadIdx.x) >> 6;
    int lane = threadIdx.x & 63;
    if (wid >= N_NODES) return;
    int b = nodes[2 * wid];
    float2 hu = *(const float2*)&h_user[b * DIM + lane * 2];
    float2 ht = *(const float2*)&out[(size_t)wid * DIM + lane * 2];
    float2 w0 = *(const float2*)&Wsc[lane * 2];
    float2 w1 = *(const float2*)&Wsc[DIM + lane * 2];
    float p = hu.x * w0.x + hu.y * w0.y + ht.x * w1.x + ht.y * w1.y;
#pragma unroll
    for (int off = 32; off; off >>= 1) p += __shfl_xor(p, off);
    float alpha = 1.f / (1.f + expf(-(p + bsc[0])));
    float2 o = make_float2(alpha * ht.x, alpha * ht.y);
    *(float2*)&out[(size_t)wid * DIM + lane * 2] = o;
}

extern "C" void kernel_launch(void* const* d_in, const int* in_sizes, int n_in,
                              void* d_out, int out_size, void* d_ws, size_t ws_size,
                              hipStream_t stream)
{
    const float* hidden = (const float*)d_in[0];
    const float* rela   = (const float*)d_in[1];
    const float* W_agg  = (const float*)d_in[2];
    const float* b_agg  = (const float*)d_in[3];
    const float* W_sc   = (const float*)d_in[4];
    const float* b_sc   = (const float*)d_in[5];
    const int* edges    = (const int*)d_in[6];
    const int* nodes    = (const int*)d_in[7];
    const int* q_sub    = (const int*)d_in[8];
    const int* old_idx  = (const int*)d_in[9];
    float* out = (float*)d_out;

    char* p = (char*)d_ws;
    auto carve = [&](size_t bytes) { char* r = p; p += (bytes + 255) & ~255ULL; return r; };
    float*    sum   = (float*)   carve((size_t)N_NODES * DIM * 4);
    float*    sumsq = (float*)   carve((size_t)N_NODES * DIM * 4);
    unsigned* maxe  = (unsigned*)carve((size_t)N_NODES * DIM * 4);
    unsigned* mine  = (unsigned*)carve((size_t)N_NODES * DIM * 4);
    float*    deg   = (float*)   carve((size_t)N_NODES * 4);
    int*      inv   = (int*)     carve((size_t)N_NODES * 4);
    float*    amp   = (float*)   carve((size_t)N_NODES * 4);
    float*    att   = (float*)   carve((size_t)N_NODES * 4);
    int*      user_idx = (int*)  carve(BATCH * 4);
    float*    h_user   = (float*)carve(BATCH * DIM * 4);

    int nd_blocks = (N_NODES * DIM + 255) / 256;
    k_init<<<nd_blocks, 256, 0, stream>>>(sum, sumsq, maxe, mine, deg, inv, user_idx);
    k_scatter<<<(N_NODES + 255) / 256, 256, 0, stream>>>(old_idx, nodes, q_sub, inv, user_idx);
    k_edges<<<N_EDGES / 4, 256, 0, stream>>>(hidden, rela, edges, sum, sumsq, maxe, mine, deg);
    k_finalize<<<nd_blocks, 256, 0, stream>>>(sum, sumsq, maxe, mine, deg, amp, att);
    k_gemm<<<(N_NODES + BM - 1) / BM, 256, 0, stream>>>(sum, (float*)maxe, (float*)mine, sumsq,
                                                        amp, att, inv, hidden, W_agg, b_agg, out);
    k_user<<<4, 256, 0, stream>>>(user_idx, out, h_user);
    k_score<<<(N_NODES * 64 + 255) / 256, 256, 0, stream>>>(h_user, nodes, W_sc, b_sc, out);
}

// Round 5
// 2066.415 us; speedup vs baseline: 2.0355x; 2.0355x over previous
//
#include <hip/hip_runtime.h>
#include <math.h>

#define N_NODES 100000
#define N_PREV  80000
#define N_EDGES 1000000
#define N_REL   43
#define DIM     128
#define BATCH   8
#define KTOT    1664   // 13*128

__global__ void k_setup(int* __restrict__ cnt, int* __restrict__ inv,
                        int* __restrict__ user_idx) {
    int i = blockIdx.x * blockDim.x + threadIdx.x;
    if (i < N_NODES) { cnt[i] = 0; inv[i] = -1; }
    if (i < BATCH) user_idx[i] = 0x7FFFFFFF;
}

__global__ void k_scatter(const int* __restrict__ old_idx, const int* __restrict__ nodes,
                          const int* __restrict__ q_sub, int* __restrict__ inv,
                          int* __restrict__ user_idx) {
    int i = blockIdx.x * blockDim.x + threadIdx.x;
    if (i < N_PREV) inv[old_idx[i]] = i;
    if (i < N_NODES) {
        int b = nodes[2 * i], e = nodes[2 * i + 1];
        if (b >= 0 && b < BATCH && q_sub[b] == e) atomicMin(&user_idx[b], i);
    }
}

__global__ void k_count(const int* __restrict__ edges, int* __restrict__ cnt) {
    int i = blockIdx.x * blockDim.x + threadIdx.x;
    if (i < N_EDGES) atomicAdd(&cnt[edges[i * 6 + 5]], 1);
}

// squared norms of hidden rows (0..N_PREV-1) and rela rows (N_PREV..N_PREV+42)
__global__ __launch_bounds__(256) void k_norms(const float* __restrict__ hidden,
                                               const float* __restrict__ rela,
                                               float* __restrict__ hnorm2,
                                               float* __restrict__ rnorm2) {
    int wid = (blockIdx.x * blockDim.x + threadIdx.x) >> 6;
    int lane = threadIdx.x & 63;
    if (wid >= N_PREV + N_REL) return;
    const float* src = (wid < N_PREV) ? &hidden[(size_t)wid * DIM]
                                      : &rela[(size_t)(wid - N_PREV) * DIM];
    float2 v = *(const float2*)&src[lane * 2];
    float p = v.x * v.x + v.y * v.y;
#pragma unroll
    for (int off = 32; off; off >>= 1) p += __shfl_xor(p, off);
    if (lane == 0) {
        if (wid < N_PREV) hnorm2[wid] = p;
        else rnorm2[wid - N_PREV] = p;
    }
}

// single-block exclusive scan of cnt[N_NODES] -> offsets[N_NODES+1], cursor copy
__global__ __launch_bounds__(1024) void k_scan(const int* __restrict__ cnt,
                                               int* __restrict__ offsets,
                                               int* __restrict__ cursor) {
    __shared__ int part[1024];
    int tid = threadIdx.x;
    const int CH = (N_NODES + 1023) / 1024;   // 98
    int base = tid * CH;
    int s = 0;
    for (int i = 0; i < CH; i++) {
        int idx = base + i;
        if (idx < N_NODES) s += cnt[idx];
    }
    part[tid] = s;
    __syncthreads();
    for (int off = 1; off < 1024; off <<= 1) {
        int v = (tid >= off) ? part[tid - off] : 0;
        __syncthreads();
        part[tid] += v;
        __syncthreads();
    }
    int run = part[tid] - s;   // exclusive base for this chunk
    for (int i = 0; i < CH; i++) {
        int idx = base + i;
        if (idx < N_NODES) {
            offsets[idx] = run;
            cursor[idx] = run;
            run += cnt[idx];
        }
    }
    if (tid == 1023) offsets[N_NODES] = part[1023];
}

// per-edge: msg = alpha*hidden[sub] + beta*rela[rel]; only pc needs a reduction
__global__ __launch_bounds__(256) void k_msg(
    const float* __restrict__ hidden, const float* __restrict__ rela,
    const int* __restrict__ edges,
    const float* __restrict__ hnorm2, const float* __restrict__ rnorm2,
    int* __restrict__ cursor, int4* __restrict__ recs)
{
    int wid = (blockIdx.x * blockDim.x + threadIdx.x) >> 6;
    int lane = threadIdx.x & 63;
    if (wid >= N_EDGES) return;
    int sub = edges[wid * 6 + 4];
    int rel = edges[wid * 6 + 2];
    int obj = edges[wid * 6 + 5];

    float2 u = *(const float2*)&hidden[sub * DIM + lane * 2];
    float2 r = *(const float2*)&rela[rel * DIM + lane * 2];
    float pc = u.x * r.x + u.y * r.y;
#pragma unroll
    for (int off = 32; off; off >>= 1) pc += __shfl_xor(pc, off);

    float ps = hnorm2[sub];
    float pr = rnorm2[rel];

    const float MAXN = 0.996f;   // (1-EPS_BALL)/sqrt(C)
    float ns = fmaxf(sqrtf(ps), 1e-15f);
    float cs = fminf(tanhf(fminf(ns, 15.f)), MAXN);
    float sx = cs / ns;               // x = sx*hs, ||x|| = cs
    float x2 = cs * cs;
    float nr = fmaxf(sqrtf(pr), 1e-15f);
    float cr = fminf(tanhf(fminf(nr, 15.f)), MAXN);
    float sy = cr / nr;
    float y2 = cr * cr;
    float xy = pc * sx * sy;
    float ca = 1.f + 2.f * xy + y2;
    float cb = 1.f - x2;
    float den = fmaxf(1.f + 2.f * xy + x2 * y2, 1e-15f);
    float id = 1.f / den;
    // ||m||^2 analytic: id^2 * (ca^2 x2 + 2 ca cb xy + cb^2 y2)
    float pm = fmaxf((ca * ca * x2 + 2.f * ca * cb * xy + cb * cb * y2) * id * id, 0.f);
    float nm = fmaxf(sqrtf(pm), 1e-15f);
    float a  = atanhf(fminf(nm, MAXN));
    float sc = a / nm;
    float alpha = sc * id * ca * sx;
    float beta  = sc * id * cb * sy;

    if (lane == 0) {
        int pos = atomicAdd(&cursor[obj], 1);
        recs[pos] = make_int4(sub, rel, __float_as_int(alpha), __float_as_int(beta));
    }
}

// wave per node: walk sorted records, accumulate in registers, fused finalize
__global__ __launch_bounds__(256) void k_agg(
    const float* __restrict__ hidden, const float* __restrict__ rela,
    const int4* __restrict__ recs, const int* __restrict__ offsets,
    float* __restrict__ mean_, float* __restrict__ mx_,
    float* __restrict__ mn_, float* __restrict__ sd_,
    float* __restrict__ amp, float* __restrict__ att)
{
    int node = blockIdx.x * 4 + (threadIdx.x >> 6);
    int lane = threadIdx.x & 63;
    if (node >= N_NODES) return;
    int beg = offsets[node], end = offsets[node + 1];
    float s0 = 0.f, s1 = 0.f, q0 = 0.f, q1 = 0.f;
    float mx0 = -INFINITY, mx1 = -INFINITY, mn0 = INFINITY, mn1 = INFINITY;
    for (int e = beg; e < end; ++e) {
        int4 rc = recs[e];
        float al = __int_as_float(rc.z), be = __int_as_float(rc.w);
        float2 u = *(const float2*)&hidden[rc.x * DIM + lane * 2];
        float2 r = *(const float2*)&rela[rc.y * DIM + lane * 2];
        float m0 = al * u.x + be * r.x;
        float m1 = al * u.y + be * r.y;
        s0 += m0; s1 += m1;
        q0 = fmaf(m0, m0, q0); q1 = fmaf(m1, m1, q1);
        mx0 = fmaxf(mx0, m0); mx1 = fmaxf(mx1, m1);
        mn0 = fminf(mn0, m0); mn1 = fminf(mn1, m1);
    }
    float d  = (float)(end - beg);
    float d1 = fmaxf(d, 1.f);
    float me0 = s0 / d1, me1 = s1 / d1;
    float sd0 = sqrtf(fmaxf(q0 / d1 - me0 * me0, 0.f) + 1e-10f);
    float sd1 = sqrtf(fmaxf(q1 / d1 - me1 * me1, 0.f) + 1e-10f);
    bool has = d > 0.f;
    if (!has) { mx0 = mx1 = mn0 = mn1 = 0.f; }
    int base = node * DIM + lane * 2;
    *(float2*)&mean_[base] = make_float2(me0, me1);
    *(float2*)&sd_[base]   = make_float2(sd0, sd1);
    *(float2*)&mx_[base]   = make_float2(mx0, mx1);
    *(float2*)&mn_[base]   = make_float2(mn0, mn1);
    if (lane == 0) {
        float logd = log1pf(d);
        amp[node] = logd;                       // logd / PNA_DELTA
        att[node] = 1.f / fmaxf(logd, 1e-5f);   // PNA_DELTA / max(logd,1e-5)
    }
}

// h_tilde = feat @ W_agg + b_agg   (M=100000, K=1664, N=128), f32 VALU
#define BM 64
#define BK 32
__global__ __launch_bounds__(256) void k_gemm(
    const float* __restrict__ mean_, const float* __restrict__ mx_,
    const float* __restrict__ mn_, const float* __restrict__ sd_,
    const float* __restrict__ amp, const float* __restrict__ att,
    const int* __restrict__ inv, const float* __restrict__ hidden,
    const float* __restrict__ W, const float* __restrict__ b,
    float* __restrict__ out)
{
    __shared__ float As[BM][BK + 1];   // [64][33]
    __shared__ float Ws[BK][DIM];      // [32][128]
    int tid = threadIdx.x;
    int n0 = blockIdx.x * BM;
    int tm = tid >> 4;   // 0..15 -> 4 nodes each
    int tn = tid & 15;   // 0..15 -> 8 outputs each
    float acc[4][8];
#pragma unroll
    for (int q = 0; q < 4; q++)
#pragma unroll
        for (int rr = 0; rr < 8; rr++) acc[q][rr] = 0.f;

    const float* bufs[4] = {mean_, mx_, mn_, sd_};

    for (int k0 = 0; k0 < KTOT; k0 += BK) {
#pragma unroll
        for (int i = 0; i < 8; i++) {
            int idx = tid + i * 256;
            int m  = idx >> 5;
            int kk = idx & 31;
            int n = n0 + m; if (n >= N_NODES) n = N_NODES - 1;
            int kg = k0 + kk;
            float v;
            if (kg < 1536) {
                int seg = kg >> 9;       // 0:agg 1:agg*amp 2:agg*att
                int j = kg & 511;
                v = bufs[j >> 7][n * DIM + (j & 127)];
                if (seg == 1) v *= amp[n];
                else if (seg == 2) v *= att[n];
            } else {
                int ii = inv[n];
                v = (ii >= 0) ? hidden[ii * DIM + (kg - 1536)] : 0.f;
            }
            As[m][kk] = v;
        }
#pragma unroll
        for (int i = 0; i < 4; i++) {
            int idx = tid + i * 256;
            int kk = idx >> 5;
            int j4 = idx & 31;
            *(float4*)&Ws[kk][j4 * 4] = *(const float4*)&W[(size_t)(k0 + kk) * DIM + j4 * 4];
        }
        __syncthreads();
#pragma unroll
        for (int kk = 0; kk < BK; kk++) {
            float a[4];
#pragma unroll
            for (int q = 0; q < 4; q++) a[q] = As[tm * 4 + q][kk];
            float4 w0 = *(float4*)&Ws[kk][tn * 8];
            float4 w1 = *(float4*)&Ws[kk][tn * 8 + 4];
            float w[8] = {w0.x, w0.y, w0.z, w0.w, w1.x, w1.y, w1.z, w1.w};
#pragma unroll
            for (int q = 0; q < 4; q++)
#pragma unroll
                for (int rr = 0; rr < 8; rr++) acc[q][rr] += a[q] * w[rr];
        }
        __syncthreads();
    }
#pragma unroll
    for (int q = 0; q < 4; q++) {
        int n = n0 + tm * 4 + q;
        if (n < N_NODES) {
            float4 o0 = make_float4(acc[q][0] + b[tn * 8 + 0], acc[q][1] + b[tn * 8 + 1],
                                    acc[q][2] + b[tn * 8 + 2], acc[q][3] + b[tn * 8 + 3]);
            float4 o1 = make_float4(acc[q][4] + b[tn * 8 + 4], acc[q][5] + b[tn * 8 + 5],
                                    acc[q][6] + b[tn * 8 + 6], acc[q][7] + b[tn * 8 + 7]);
            *(float4*)&out[(size_t)n * DIM + tn * 8] = o0;
            *(float4*)&out[(size_t)n * DIM + tn * 8 + 4] = o1;
        }
    }
}

__global__ void k_user(const int* __restrict__ user_idx, const float* __restrict__ htilde,
                       float* __restrict__ h_user) {
    int t = blockIdx.x * blockDim.x + threadIdx.x;
    if (t < BATCH * DIM) {
        int b = t >> 7, d = t & 127;
        int idx = user_idx[b];
        if (idx == 0x7FFFFFFF) idx = 0;   // argmax of all-False -> 0
        h_user[t] = htilde[(size_t)idx * DIM + d];
    }
}

__global__ __launch_bounds__(256) void k_score(
    const float* __restrict__ h_user, const int* __restrict__ nodes,
    const float* __restrict__ Wsc, const float* __restrict__ bsc,
    float* __restrict__ out)
{
    int wid = (blockIdx.x * blockDim.x + threadIdx.x) >> 6;
    int lane = threadIdx.x & 63;
    if (wid >= N_NODES) return;
    int b = nodes[2 * wid];
    float2 hu = *(const float2*)&h_user[b * DIM + lane * 2];
    float2 ht = *(const float2*)&out[(size_t)wid * DIM + lane * 2];
    float2 w0 = *(const float2*)&Wsc[lane * 2];
    float2 w1 = *(const float2*)&Wsc[DIM + lane * 2];
    float p = hu.x * w0.x + hu.y * w0.y + ht.x * w1.x + ht.y * w1.y;
#pragma unroll
    for (int off = 32; off; off >>= 1) p += __shfl_xor(p, off);
    float alpha = 1.f / (1.f + expf(-(p + bsc[0])));
    float2 o = make_float2(alpha * ht.x, alpha * ht.y);
    *(float2*)&out[(size_t)wid * DIM + lane * 2] = o;
}

extern "C" void kernel_launch(void* const* d_in, const int* in_sizes, int n_in,
                              void* d_out, int out_size, void* d_ws, size_t ws_size,
                              hipStream_t stream)
{
    const float* hidden = (const float*)d_in[0];
    const float* rela   = (const float*)d_in[1];
    const float* W_agg  = (const float*)d_in[2];
    const float* b_agg  = (const float*)d_in[3];
    const float* W_sc   = (const float*)d_in[4];
    const float* b_sc   = (const float*)d_in[5];
    const int* edges    = (const int*)d_in[6];
    const int* nodes    = (const int*)d_in[7];
    const int* q_sub    = (const int*)d_in[8];
    const int* old_idx  = (const int*)d_in[9];
    float* out = (float*)d_out;

    char* p = (char*)d_ws;
    auto carve = [&](size_t bytes) { char* r = p; p += (bytes + 255) & ~255ULL; return r; };
    float* aggMean = (float*)carve((size_t)N_NODES * DIM * 4);
    float* aggMx   = (float*)carve((size_t)N_NODES * DIM * 4);
    float* aggMn   = (float*)carve((size_t)N_NODES * DIM * 4);
    float* aggSd   = (float*)carve((size_t)N_NODES * DIM * 4);
    int4*  recs    = (int4*) carve((size_t)N_EDGES * 16);
    float* hnorm2  = (float*)carve((size_t)N_PREV * 4);
    float* rnorm2  = (float*)carve(N_REL * 4);
    int*   cnt     = (int*)  carve((size_t)N_NODES * 4);
    int*   offsets = (int*)  carve(((size_t)N_NODES + 1) * 4);
    int*   cursor  = (int*)  carve((size_t)N_NODES * 4);
    int*   inv     = (int*)  carve((size_t)N_NODES * 4);
    float* amp     = (float*)carve((size_t)N_NODES * 4);
    float* att     = (float*)carve((size_t)N_NODES * 4);
    int*   user_idx = (int*) carve(BATCH * 4);
    float* h_user   = (float*)carve(BATCH * DIM * 4);

    k_setup<<<(N_NODES + 255) / 256, 256, 0, stream>>>(cnt, inv, user_idx);
    k_scatter<<<(N_NODES + 255) / 256, 256, 0, stream>>>(old_idx, nodes, q_sub, inv, user_idx);
    k_count<<<(N_EDGES + 255) / 256, 256, 0, stream>>>(edges, cnt);
    k_norms<<<(N_PREV + N_REL + 3) / 4, 256, 0, stream>>>(hidden, rela, hnorm2, rnorm2);
    k_scan<<<1, 1024, 0, stream>>>(cnt, offsets, cursor);
    k_msg<<<N_EDGES / 4, 256, 0, stream>>>(hidden, rela, edges, hnorm2, rnorm2, cursor, recs);
    k_agg<<<(N_NODES + 3) / 4, 256, 0, stream>>>(hidden, rela, recs, offsets,
                                                 aggMean, aggMx, aggMn, aggSd, amp, att);
    k_gemm<<<(N_NODES + BM - 1) / BM, 256, 0, stream>>>(aggMean, aggMx, aggMn, aggSd,
                                                        amp, att, inv, hidden, W_agg, b_agg, out);
    k_user<<<4, 256, 0, stream>>>(user_idx, out, h_user);
    k_score<<<(N_NODES * 64 + 255) / 256, 256, 0, stream>>>(h_user, nodes, W_sc, b_sc, out);
}

// Round 9
// 1047.728 us; speedup vs baseline: 4.0145x; 1.9723x over previous
//
#include <hip/hip_runtime.h>
#include <math.h>

#define N_NODES 100000
#define N_PREV  80000
#define N_EDGES 1000000
#define N_REL   43
#define DIM     128
#define BATCH   8
#define KA      640    // A' width: 512 agg + 128 h_prev
#define NB      384    // B' cols: 3 groups x 128

typedef __attribute__((ext_vector_type(8))) short bf16x8;
typedef __attribute__((ext_vector_type(4))) float f32x4;

// f32 -> bf16 round-to-nearest-even (finite inputs)
__device__ __forceinline__ unsigned short f2bf(float f) {
    unsigned u = __float_as_uint(f);
    unsigned r = (u + 0x7FFFu + ((u >> 16) & 1u)) >> 16;
    return (unsigned short)r;
}
__device__ __forceinline__ void st_bf2(unsigned short* p, float a, float b) {
    *(unsigned*)p = (unsigned)f2bf(a) | ((unsigned)f2bf(b) << 16);
}

__global__ void k_setup(int* __restrict__ cnt, int* __restrict__ inv,
                        int* __restrict__ user_idx) {
    int i = blockIdx.x * blockDim.x + threadIdx.x;
    if (i < N_NODES) { cnt[i] = 0; inv[i] = -1; }
    if (i < BATCH) user_idx[i] = 0x7FFFFFFF;
}

__global__ void k_scatter(const int* __restrict__ old_idx, const int* __restrict__ nodes,
                          const int* __restrict__ q_sub, int* __restrict__ inv,
                          int* __restrict__ user_idx) {
    int i = blockIdx.x * blockDim.x + threadIdx.x;
    if (i < N_PREV) inv[old_idx[i]] = i;
    if (i < N_NODES) {
        int b = nodes[2 * i], e = nodes[2 * i + 1];
        if (b >= 0 && b < BATCH && q_sub[b] == e) atomicMin(&user_idx[b], i);
    }
}

__global__ void k_count(const int* __restrict__ edges, int* __restrict__ cnt) {
    int i = blockIdx.x * blockDim.x + threadIdx.x;
    if (i < N_EDGES) atomicAdd(&cnt[edges[i * 6 + 5]], 1);
}

// Build B' bf16 [NB][KA]:  c' = g*128+c.  k<512: W[(g*512+k)][c];  k>=512: g==0 ? W[1536+k-512][c] : 0
__global__ void k_convW(const float* __restrict__ W, unsigned short* __restrict__ Wt) {
    int i = blockIdx.x * blockDim.x + threadIdx.x;
    if (i >= NB * KA) return;
    int cp = i / KA, kp = i - cp * KA;
    int g = cp >> 7, c = cp & 127;
    float v;
    if (kp < 512) v = W[(size_t)(g * 512 + kp) * DIM + c];
    else          v = (g == 0) ? W[(size_t)(1536 + kp - 512) * DIM + c] : 0.f;
    Wt[(size_t)cp * KA + kp] = f2bf(v);
}

// squared norms of hidden rows and rela rows
__global__ __launch_bounds__(256) void k_norms(const float* __restrict__ hidden,
                                               const float* __restrict__ rela,
                                               float* __restrict__ hnorm2,
                                               float* __restrict__ rnorm2) {
    int wid = (blockIdx.x * blockDim.x + threadIdx.x) >> 6;
    int lane = threadIdx.x & 63;
    if (wid >= N_PREV + N_REL) return;
    const float* src = (wid < N_PREV) ? &hidden[(size_t)wid * DIM]
                                      : &rela[(size_t)(wid - N_PREV) * DIM];
    float2 v = *(const float2*)&src[lane * 2];
    float p = v.x * v.x + v.y * v.y;
#pragma unroll
    for (int off = 32; off; off >>= 1) p += __shfl_xor(p, off);
    if (lane == 0) {
        if (wid < N_PREV) hnorm2[wid] = p;
        else rnorm2[wid - N_PREV] = p;
    }
}

// single-block exclusive scan of cnt[N_NODES] -> offsets[N_NODES+1], cursor copy
__global__ __launch_bounds__(1024) void k_scan(const int* __restrict__ cnt,
                                               int* __restrict__ offsets,
                                               int* __restrict__ cursor) {
    __shared__ int part[1024];
    int tid = threadIdx.x;
    const int CH = (N_NODES + 1023) / 1024;   // 98
    int base = tid * CH;
    int s = 0;
    for (int i = 0; i < CH; i++) {
        int idx = base + i;
        if (idx < N_NODES) s += cnt[idx];
    }
    part[tid] = s;
    __syncthreads();
    for (int off = 1; off < 1024; off <<= 1) {
        int v = (tid >= off) ? part[tid - off] : 0;
        __syncthreads();
        part[tid] += v;
        __syncthreads();
    }
    int run = part[tid] - s;
    for (int i = 0; i < CH; i++) {
        int idx = base + i;
        if (idx < N_NODES) {
            offsets[idx] = run;
            cursor[idx] = run;
            run += cnt[idx];
        }
    }
    if (tid == 1023) offsets[N_NODES] = part[1023];
}

// per-edge: msg = alpha*hidden[sub] + beta*rela[rel]; only pc needs a reduction
__global__ __launch_bounds__(256) void k_msg(
    const float* __restrict__ hidden, const float* __restrict__ rela,
    const int* __restrict__ edges,
    const float* __restrict__ hnorm2, const float* __restrict__ rnorm2,
    int* __restrict__ cursor, int4* __restrict__ recs)
{
    int wid = (blockIdx.x * blockDim.x + threadIdx.x) >> 6;
    int lane = threadIdx.x & 63;
    if (wid >= N_EDGES) return;
    int sub = edges[wid * 6 + 4];
    int rel = edges[wid * 6 + 2];
    int obj = edges[wid * 6 + 5];

    float2 u = *(const float2*)&hidden[sub * DIM + lane * 2];
    float2 r = *(const float2*)&rela[rel * DIM + lane * 2];
    float pc = u.x * r.x + u.y * r.y;
#pragma unroll
    for (int off = 32; off; off >>= 1) pc += __shfl_xor(pc, off);

    float ps = hnorm2[sub];
    float pr = rnorm2[rel];

    const float MAXN = 0.996f;   // (1-EPS_BALL)/sqrt(C)
    float ns = fmaxf(sqrtf(ps), 1e-15f);
    float cs = fminf(tanhf(fminf(ns, 15.f)), MAXN);
    float sx = cs / ns;
    float x2 = cs * cs;
    float nr = fmaxf(sqrtf(pr), 1e-15f);
    float cr = fminf(tanhf(fminf(nr, 15.f)), MAXN);
    float sy = cr / nr;
    float y2 = cr * cr;
    float xy = pc * sx * sy;
    float ca = 1.f + 2.f * xy + y2;
    float cb = 1.f - x2;
    float den = fmaxf(1.f + 2.f * xy + x2 * y2, 1e-15f);
    float id = 1.f / den;
    float pm = fmaxf((ca * ca * x2 + 2.f * ca * cb * xy + cb * cb * y2) * id * id, 0.f);
    float nm = fmaxf(sqrtf(pm), 1e-15f);
    float a  = atanhf(fminf(nm, MAXN));
    float sc = a / nm;
    float alpha = sc * id * ca * sx;
    float beta  = sc * id * cb * sy;

    if (lane == 0) {
        int pos = atomicAdd(&cursor[obj], 1);
        recs[pos] = make_int4(sub, rel, __float_as_int(alpha), __float_as_int(beta));
    }
}

// wave per node: walk sorted records; write A' row [mean,mx,mn,sd(512) | h_prev(128)] bf16 + amp/att
__global__ __launch_bounds__(256) void k_agg(
    const float* __restrict__ hidden, const float* __restrict__ rela,
    const int4* __restrict__ recs, const int* __restrict__ offsets,
    const int* __restrict__ inv, unsigned short* __restrict__ Ap,
    float* __restrict__ amp, float* __restrict__ att)
{
    int node = blockIdx.x * 4 + (threadIdx.x >> 6);
    int lane = threadIdx.x & 63;
    if (node >= N_NODES) return;
    int beg = offsets[node], end = offsets[node + 1];
    float s0 = 0.f, s1 = 0.f, q0 = 0.f, q1 = 0.f;
    float mx0 = -INFINITY, mx1 = -INFINITY, mn0 = INFINITY, mn1 = INFINITY;
    for (int e = beg; e < end; ++e) {
        int4 rc = recs[e];
        float al = __int_as_float(rc.z), be = __int_as_float(rc.w);
        float2 u = *(const float2*)&hidden[rc.x * DIM + lane * 2];
        float2 r = *(const float2*)&rela[rc.y * DIM + lane * 2];
        float m0 = al * u.x + be * r.x;
        float m1 = al * u.y + be * r.y;
        s0 += m0; s1 += m1;
        q0 = fmaf(m0, m0, q0); q1 = fmaf(m1, m1, q1);
        mx0 = fmaxf(mx0, m0); mx1 = fmaxf(mx1, m1);
        mn0 = fminf(mn0, m0); mn1 = fminf(mn1, m1);
    }
    float d  = (float)(end - beg);
    float d1 = fmaxf(d, 1.f);
    float me0 = s0 / d1, me1 = s1 / d1;
    float sd0 = sqrtf(fmaxf(q0 / d1 - me0 * me0, 0.f) + 1e-10f);
    float sd1 = sqrtf(fmaxf(q1 / d1 - me1 * me1, 0.f) + 1e-10f);
    if (!(d > 0.f)) { mx0 = mx1 = mn0 = mn1 = 0.f; }

    unsigned short* row = Ap + (size_t)node * KA;
    int o = lane * 2;
    st_bf2(row +   0 + o, me0, me1);
    st_bf2(row + 128 + o, mx0, mx1);
    st_bf2(row + 256 + o, mn0, mn1);
    st_bf2(row + 384 + o, sd0, sd1);
    int ii = inv[node];
    float h0 = 0.f, h1 = 0.f;
    if (ii >= 0) {
        float2 h = *(const float2*)&hidden[(size_t)ii * DIM + o];
        h0 = h.x; h1 = h.y;
    }
    st_bf2(row + 512 + o, h0, h1);
    if (lane == 0) {
        float logd = log1pf(d);
        amp[node] = logd;                       // logd / PNA_DELTA
        att[node] = 1.f / fmaxf(logd, 1e-5f);   // PNA_DELTA / max(logd,1e-5)
    }
}

// C[100000][384] = A'[100000][640] @ B'^T[384][640]; fused combine:
// out[n][c] = C[n][c] + amp[n]*C[n][128+c] + att[n]*C[n][256+c] + bias[c]
// 512 thr = 8 waves (2m x 4n); block tile 128x384; wave tile 64 rows x {32 cols x 3 groups}
__global__ __launch_bounds__(512) void k_gemm_mfma(
    const unsigned short* __restrict__ Ap,   // [N_NODES][KA]
    const unsigned short* __restrict__ Wt,   // [NB][KA]
    const float* __restrict__ amp, const float* __restrict__ att,
    const float* __restrict__ bias, float* __restrict__ out)
{
    __shared__ uint4 As4[128 * 8];   // [row][chunk ^ (row&7)]
    __shared__ uint4 Bs4[NB * 8];    // [col'][chunk ^ (col'&7)]
    int tid = threadIdx.x;
    int wave = tid >> 6, lane = tid & 63;
    int wm = wave >> 2, wn = wave & 3;       // 2 x 4
    int l15 = lane & 15, l4 = lane >> 4;
    int m0 = blockIdx.x * 128;

    f32x4 acc[4][6];                         // [mi][g*2+t]
#pragma unroll
    for (int mi = 0; mi < 4; ++mi)
#pragma unroll
        for (int nj = 0; nj < 6; ++nj) acc[mi][nj] = (f32x4){0.f, 0.f, 0.f, 0.f};

    for (int k0 = 0; k0 < KA; k0 += 64) {
#pragma unroll
        for (int it = 0; it < 2; ++it) {     // A: 1024 chunks
            int c = tid + it * 512;
            int row = c >> 3, ko = c & 7;
            int gr = m0 + row; if (gr >= N_NODES) gr = N_NODES - 1;
            As4[row * 8 + (ko ^ (row & 7))] =
                *((const uint4*)(Ap + (size_t)gr * KA + k0) + ko);
        }
#pragma unroll
        for (int it = 0; it < 6; ++it) {     // B: 3072 chunks
            int c = tid + it * 512;
            int row = c >> 3, ko = c & 7;
            Bs4[row * 8 + (ko ^ (row & 7))] =
                *((const uint4*)(Wt + (size_t)row * KA + k0) + ko);
        }
        __syncthreads();
#pragma unroll
        for (int h = 0; h < 2; ++h) {        // two K=32 halves
            int kc = h * 4 + l4;
            bf16x8 af[4], bfr[6];
#pragma unroll
            for (int mi = 0; mi < 4; ++mi) {
                int r = wm * 64 + mi * 16 + l15;
                uint4 t = As4[r * 8 + (kc ^ (r & 7))];
                af[mi] = *(bf16x8*)&t;
            }
#pragma unroll
            for (int g = 0; g < 3; ++g)
#pragma unroll
                for (int t2 = 0; t2 < 2; ++t2) {
                    int cc = g * 128 + wn * 32 + t2 * 16 + l15;
                    uint4 t = Bs4[cc * 8 + (kc ^ (cc & 7))];
                    bfr[g * 2 + t2] = *(bf16x8*)&t;
                }
#pragma unroll
            for (int mi = 0; mi < 4; ++mi)
#pragma unroll
                for (int nj = 0; nj < 6; ++nj)
                    acc[mi][nj] = __builtin_amdgcn_mfma_f32_16x16x32_bf16(
                        af[mi], bfr[nj], acc[mi][nj], 0, 0, 0);
        }
        __syncthreads();
    }
    // epilogue: D col = lane&15, row = (lane>>4)*4 + reg  [m89/m91]
#pragma unroll
    for (int mi = 0; mi < 4; ++mi) {
#pragma unroll
        for (int rg = 0; rg < 4; ++rg) {
            int row = m0 + wm * 64 + mi * 16 + l4 * 4 + rg;
            if (row >= N_NODES) continue;
            float am = amp[row], at = att[row];
#pragma unroll
            for (int t2 = 0; t2 < 2; ++t2) {
                int c = wn * 32 + t2 * 16 + l15;
                float v = acc[mi][t2][rg] + am * acc[mi][2 + t2][rg]
                        + at * acc[mi][4 + t2][rg] + bias[c];
                out[(size_t)row * DIM + c] = v;
            }
        }
    }
}

__global__ void k_user(const int* __restrict__ user_idx, const float* __restrict__ htilde,
                       float* __restrict__ h_user) {
    int t = blockIdx.x * blockDim.x + threadIdx.x;
    if (t < BATCH * DIM) {
        int b = t >> 7, d = t & 127;
        int idx = user_idx[b];
        if (idx == 0x7FFFFFFF) idx = 0;
        h_user[t] = htilde[(size_t)idx * DIM + d];
    }
}

__global__ __launch_bounds__(256) void k_score(
    const float* __restrict__ h_user, const int* __restrict__ nodes,
    const float* __restrict__ Wsc, const float* __restrict__ bsc,
    float* __restrict__ out)
{
    int wid = (blockIdx.x * blockDim.x + threadIdx.x) >> 6;
    int lane = threadIdx.x & 63;
    if (wid >= N_NODES) return;
    int b = nodes[2 * wid];
    float2 hu = *(const float2*)&h_user[b * DIM + lane * 2];
    float2 ht = *(const float2*)&out[(size_t)wid * DIM + lane * 2];
    float2 w0 = *(const float2*)&Wsc[lane * 2];
    float2 w1 = *(const float2*)&Wsc[DIM + lane * 2];
    float p = hu.x * w0.x + hu.y * w0.y + ht.x * w1.x + ht.y * w1.y;
#pragma unroll
    for (int off = 32; off; off >>= 1) p += __shfl_xor(p, off);
    float alpha = 1.f / (1.f + expf(-(p + bsc[0])));
    float2 o = make_float2(alpha * ht.x, alpha * ht.y);
    *(float2*)&out[(size_t)wid * DIM + lane * 2] = o;
}

extern "C" void kernel_launch(void* const* d_in, const int* in_sizes, int n_in,
                              void* d_out, int out_size, void* d_ws, size_t ws_size,
                              hipStream_t stream)
{
    const float* hidden = (const float*)d_in[0];
    const float* rela   = (const float*)d_in[1];
    const float* W_agg  = (const float*)d_in[2];
    const float* b_agg  = (const float*)d_in[3];
    const float* W_sc   = (const float*)d_in[4];
    const float* b_sc   = (const float*)d_in[5];
    const int* edges    = (const int*)d_in[6];
    const int* nodes    = (const int*)d_in[7];
    const int* q_sub    = (const int*)d_in[8];
    const int* old_idx  = (const int*)d_in[9];
    float* out = (float*)d_out;

    char* p = (char*)d_ws;
    auto carve = [&](size_t bytes) { char* r = p; p += (bytes + 255) & ~255ULL; return r; };
    unsigned short* Ap  = (unsigned short*)carve((size_t)N_NODES * KA * 2);  // 128 MB
    unsigned short* Wtb = (unsigned short*)carve((size_t)NB * KA * 2);       // 0.5 MB
    int4*  recs    = (int4*) carve((size_t)N_EDGES * 16);                    // 16 MB
    float* hnorm2  = (float*)carve((size_t)N_PREV * 4);
    float* rnorm2  = (float*)carve(N_REL * 4);
    int*   cnt     = (int*)  carve((size_t)N_NODES * 4);
    int*   offsets = (int*)  carve(((size_t)N_NODES + 1) * 4);
    int*   cursor  = (int*)  carve((size_t)N_NODES * 4);
    int*   inv     = (int*)  carve((size_t)N_NODES * 4);
    float* amp     = (float*)carve((size_t)N_NODES * 4);
    float* att     = (float*)carve((size_t)N_NODES * 4);
    int*   user_idx = (int*) carve(BATCH * 4);
    float* h_user   = (float*)carve(BATCH * DIM * 4);

    k_setup<<<(N_NODES + 255) / 256, 256, 0, stream>>>(cnt, inv, user_idx);
    k_scatter<<<(N_NODES + 255) / 256, 256, 0, stream>>>(old_idx, nodes, q_sub, inv, user_idx);
    k_count<<<(N_EDGES + 255) / 256, 256, 0, stream>>>(edges, cnt);
    k_convW<<<(NB * KA + 255) / 256, 256, 0, stream>>>(W_agg, Wtb);
    k_norms<<<(N_PREV + N_REL + 3) / 4, 256, 0, stream>>>(hidden, rela, hnorm2, rnorm2);
    k_scan<<<1, 1024, 0, stream>>>(cnt, offsets, cursor);
    k_msg<<<N_EDGES / 4, 256, 0, stream>>>(hidden, rela, edges, hnorm2, rnorm2, cursor, recs);
    k_agg<<<(N_NODES + 3) / 4, 256, 0, stream>>>(hidden, rela, recs, offsets, inv, Ap, amp, att);
    k_gemm_mfma<<<(N_NODES + 127) / 128, 512, 0, stream>>>(Ap, Wtb, amp, att, b_agg, out);
    k_user<<<4, 256, 0, stream>>>(user_idx, out, h_user);
    k_score<<<(N_NODES * 64 + 255) / 256, 256, 0, stream>>>(h_user, nodes, W_sc, b_sc, out);
}

// Round 11
// 961.450 us; speedup vs baseline: 4.3748x; 1.0897x over previous
//
#include <hip/hip_runtime.h>
#include <math.h>

#define N_NODES 100000
#define N_PREV  80000
#define N_EDGES 1000000
#define N_REL   43
#define DIM     128
#define BATCH   8
#define KA      640    // A' width: 512 agg + 128 h_prev
#define NB      384    // B' cols: 3 groups x 128

typedef __attribute__((ext_vector_type(8))) short bf16x8;
typedef __attribute__((ext_vector_type(4))) float f32x4;

// f32 -> bf16 round-to-nearest-even (finite inputs)
__device__ __forceinline__ unsigned short f2bf(float f) {
    unsigned u = __float_as_uint(f);
    unsigned r = (u + 0x7FFFu + ((u >> 16) & 1u)) >> 16;
    return (unsigned short)r;
}
__device__ __forceinline__ void st_bf2(unsigned short* p, float a, float b) {
    *(unsigned*)p = (unsigned)f2bf(a) | ((unsigned)f2bf(b) << 16);
}

__global__ void k_setup(int* __restrict__ cnt, int* __restrict__ inv,
                        int* __restrict__ user_idx) {
    int i = blockIdx.x * blockDim.x + threadIdx.x;
    if (i < N_NODES) { cnt[i] = 0; inv[i] = -1; }
    if (i < BATCH) user_idx[i] = 0x7FFFFFFF;
}

__global__ void k_scatter(const int* __restrict__ old_idx, const int* __restrict__ nodes,
                          const int* __restrict__ q_sub, int* __restrict__ inv,
                          int* __restrict__ user_idx) {
    int i = blockIdx.x * blockDim.x + threadIdx.x;
    if (i < N_PREV) inv[old_idx[i]] = i;
    if (i < N_NODES) {
        int b = nodes[2 * i], e = nodes[2 * i + 1];
        if (b >= 0 && b < BATCH && q_sub[b] == e) atomicMin(&user_idx[b], i);
    }
}

__global__ void k_count(const int* __restrict__ edges, int* __restrict__ cnt) {
    int i = blockIdx.x * blockDim.x + threadIdx.x;
    if (i < N_EDGES) atomicAdd(&cnt[edges[i * 6 + 5]], 1);
}

// Build B' bf16 [NB][KA]:  c' = g*128+c.  k<512: W[(g*512+k)][c];  k>=512: g==0 ? W[1536+k-512][c] : 0
__global__ void k_convW(const float* __restrict__ W, unsigned short* __restrict__ Wt) {
    int i = blockIdx.x * blockDim.x + threadIdx.x;
    if (i >= NB * KA) return;
    int cp = i / KA, kp = i - cp * KA;
    int g = cp >> 7, c = cp & 127;
    float v;
    if (kp < 512) v = W[(size_t)(g * 512 + kp) * DIM + c];
    else          v = (g == 0) ? W[(size_t)(1536 + kp - 512) * DIM + c] : 0.f;
    Wt[(size_t)cp * KA + kp] = f2bf(v);
}

// squared norms of hidden rows and rela rows
__global__ __launch_bounds__(256) void k_norms(const float* __restrict__ hidden,
                                               const float* __restrict__ rela,
                                               float* __restrict__ hnorm2,
                                               float* __restrict__ rnorm2) {
    int wid = (blockIdx.x * blockDim.x + threadIdx.x) >> 6;
    int lane = threadIdx.x & 63;
    if (wid >= N_PREV + N_REL) return;
    const float* src = (wid < N_PREV) ? &hidden[(size_t)wid * DIM]
                                      : &rela[(size_t)(wid - N_PREV) * DIM];
    float2 v = *(const float2*)&src[lane * 2];
    float p = v.x * v.x + v.y * v.y;
#pragma unroll
    for (int off = 32; off; off >>= 1) p += __shfl_xor(p, off);
    if (lane == 0) {
        if (wid < N_PREV) hnorm2[wid] = p;
        else rnorm2[wid - N_PREV] = p;
    }
}

// P[sub][rel] = hidden[sub] . rela[rel]  (wave per sub row; hidden read once)
__global__ __launch_bounds__(256) void k_dotP(
    const float* __restrict__ hidden, const float* __restrict__ rela,
    float* __restrict__ P)
{
    int wid = (blockIdx.x * blockDim.x + threadIdx.x) >> 6;
    int lane = threadIdx.x & 63;
    if (wid >= N_PREV) return;
    float2 h = *(const float2*)&hidden[(size_t)wid * DIM + lane * 2];
    for (int r = 0; r < N_REL; ++r) {
        float2 v = *(const float2*)&rela[r * DIM + lane * 2];
        float p = h.x * v.x + h.y * v.y;
#pragma unroll
        for (int off = 32; off; off >>= 1) p += __shfl_xor(p, off);
        if (lane == 0) P[(size_t)wid * N_REL + r] = p;
    }
}

// single-block exclusive scan of cnt[N_NODES] -> offsets[N_NODES+1], cursor copy
__global__ __launch_bounds__(1024) void k_scan(const int* __restrict__ cnt,
                                               int* __restrict__ offsets,
                                               int* __restrict__ cursor) {
    __shared__ int part[1024];
    int tid = threadIdx.x;
    const int CH = (N_NODES + 1023) / 1024;   // 98
    int base = tid * CH;
    int s = 0;
    for (int i = 0; i < CH; i++) {
        int idx = base + i;
        if (idx < N_NODES) s += cnt[idx];
    }
    part[tid] = s;
    __syncthreads();
    for (int off = 1; off < 1024; off <<= 1) {
        int v = (tid >= off) ? part[tid - off] : 0;
        __syncthreads();
        part[tid] += v;
        __syncthreads();
    }
    int run = part[tid] - s;
    for (int i = 0; i < CH; i++) {
        int idx = base + i;
        if (idx < N_NODES) {
            offsets[idx] = run;
            cursor[idx] = run;
            run += cnt[idx];
        }
    }
    if (tid == 1023) offsets[N_NODES] = part[1023];
}

// ONE THREAD per edge: pc gathered from P table; scalar hyperbolic math; scatter record
__global__ __launch_bounds__(256) void k_msg(
    const int* __restrict__ edges, const float* __restrict__ P,
    const float* __restrict__ hnorm2, const float* __restrict__ rnorm2,
    int* __restrict__ cursor, int4* __restrict__ recs)
{
    int i = blockIdx.x * blockDim.x + threadIdx.x;
    if (i >= N_EDGES) return;
    int rel = edges[i * 6 + 2];
    int sub = edges[i * 6 + 4];
    int obj = edges[i * 6 + 5];

    float pc = P[(size_t)sub * N_REL + rel];
    float ps = hnorm2[sub];
    float pr = rnorm2[rel];

    const float MAXN = 0.996f;   // (1-EPS_BALL)/sqrt(C)
    float ns = fmaxf(sqrtf(ps), 1e-15f);
    float cs = fminf(tanhf(fminf(ns, 15.f)), MAXN);
    float sx = cs / ns;
    float x2 = cs * cs;
    float nr = fmaxf(sqrtf(pr), 1e-15f);
    float cr = fminf(tanhf(fminf(nr, 15.f)), MAXN);
    float sy = cr / nr;
    float y2 = cr * cr;
    float xy = pc * sx * sy;
    float ca = 1.f + 2.f * xy + y2;
    float cb = 1.f - x2;
    float den = fmaxf(1.f + 2.f * xy + x2 * y2, 1e-15f);
    float id = 1.f / den;
    float pm = fmaxf((ca * ca * x2 + 2.f * ca * cb * xy + cb * cb * y2) * id * id, 0.f);
    float nm = fmaxf(sqrtf(pm), 1e-15f);
    float a  = atanhf(fminf(nm, MAXN));
    float sc = a / nm;
    float alpha = sc * id * ca * sx;
    float beta  = sc * id * cb * sy;

    int pos = atomicAdd(&cursor[obj], 1);
    recs[pos] = make_int4(sub, rel, __float_as_int(alpha), __float_as_int(beta));
}

// wave per node: walk sorted records; write A' row [mean,mx,mn,sd(512) | h_prev(128)] bf16 + amp/att
__global__ __launch_bounds__(256) void k_agg(
    const float* __restrict__ hidden, const float* __restrict__ rela,
    const int4* __restrict__ recs, const int* __restrict__ offsets,
    const int* __restrict__ inv, unsigned short* __restrict__ Ap,
    float* __restrict__ amp, float* __restrict__ att)
{
    int node = blockIdx.x * 4 + (threadIdx.x >> 6);
    int lane = threadIdx.x & 63;
    if (node >= N_NODES) return;
    int beg = offsets[node], end = offsets[node + 1];
    float s0 = 0.f, s1 = 0.f, q0 = 0.f, q1 = 0.f;
    float mx0 = -INFINITY, mx1 = -INFINITY, mn0 = INFINITY, mn1 = INFINITY;
    for (int e = beg; e < end; ++e) {
        int4 rc = recs[e];
        float al = __int_as_float(rc.z), be = __int_as_float(rc.w);
        float2 u = *(const float2*)&hidden[rc.x * DIM + lane * 2];
        float2 r = *(const float2*)&rela[rc.y * DIM + lane * 2];
        float m0 = al * u.x + be * r.x;
        float m1 = al * u.y + be * r.y;
        s0 += m0; s1 += m1;
        q0 = fmaf(m0, m0, q0); q1 = fmaf(m1, m1, q1);
        mx0 = fmaxf(mx0, m0); mx1 = fmaxf(mx1, m1);
        mn0 = fminf(mn0, m0); mn1 = fminf(mn1, m1);
    }
    float d  = (float)(end - beg);
    float d1 = fmaxf(d, 1.f);
    float me0 = s0 / d1, me1 = s1 / d1;
    float sd0 = sqrtf(fmaxf(q0 / d1 - me0 * me0, 0.f) + 1e-10f);
    float sd1 = sqrtf(fmaxf(q1 / d1 - me1 * me1, 0.f) + 1e-10f);
    if (!(d > 0.f)) { mx0 = mx1 = mn0 = mn1 = 0.f; }

    unsigned short* row = Ap + (size_t)node * KA;
    int o = lane * 2;
    st_bf2(row +   0 + o, me0, me1);
    st_bf2(row + 128 + o, mx0, mx1);
    st_bf2(row + 256 + o, mn0, mn1);
    st_bf2(row + 384 + o, sd0, sd1);
    int ii = inv[node];
    float h0 = 0.f, h1 = 0.f;
    if (ii >= 0) {
        float2 h = *(const float2*)&hidden[(size_t)ii * DIM + o];
        h0 = h.x; h1 = h.y;
    }
    st_bf2(row + 512 + o, h0, h1);
    if (lane == 0) {
        float logd = log1pf(d);
        amp[node] = logd;                       // logd / PNA_DELTA
        att[node] = 1.f / fmaxf(logd, 1e-5f);   // PNA_DELTA / max(logd,1e-5)
    }
}

// C[100000][384] = A'[100000][640] @ B'^T[384][640]; fused combine:
// out[n][c] = C[n][c] + amp[n]*C[n][128+c] + att[n]*C[n][256+c] + bias[c]
// 512 thr = 8 waves (2m x 4n); block tile 128x384; wave tile 64 rows x {32 cols x 3 groups}
__global__ __launch_bounds__(512) void k_gemm_mfma(
    const unsigned short* __restrict__ Ap,   // [N_NODES][KA]
    const unsigned short* __restrict__ Wt,   // [NB][KA]
    const float* __restrict__ amp, const float* __restrict__ att,
    const float* __restrict__ bias, float* __restrict__ out)
{
    __shared__ uint4 As4[128 * 8];   // [row][chunk ^ (row&7)]
    __shared__ uint4 Bs4[NB * 8];    // [col'][chunk ^ (col'&7)]
    int tid = threadIdx.x;
    int wave = tid >> 6, lane = tid & 63;
    int wm = wave >> 2, wn = wave & 3;       // 2 x 4
    int l15 = lane & 15, l4 = lane >> 4;
    int m0 = blockIdx.x * 128;

    f32x4 acc[4][6];                         // [mi][g*2+t]
#pragma unroll
    for (int mi = 0; mi < 4; ++mi)
#pragma unroll
        for (int nj = 0; nj < 6; ++nj) acc[mi][nj] = (f32x4){0.f, 0.f, 0.f, 0.f};

    for (int k0 = 0; k0 < KA; k0 += 64) {
#pragma unroll
        for (int it = 0; it < 2; ++it) {     // A: 1024 chunks
            int c = tid + it * 512;
            int row = c >> 3, ko = c & 7;
            int gr = m0 + row; if (gr >= N_NODES) gr = N_NODES - 1;
            As4[row * 8 + (ko ^ (row & 7))] =
                *((const uint4*)(Ap + (size_t)gr * KA + k0) + ko);
        }
#pragma unroll
        for (int it = 0; it < 6; ++it) {     // B: 3072 chunks
            int c = tid + it * 512;
            int row = c >> 3, ko = c & 7;
            Bs4[row * 8 + (ko ^ (row & 7))] =
                *((const uint4*)(Wt + (size_t)row * KA + k0) + ko);
        }
        __syncthreads();
#pragma unroll
        for (int h = 0; h < 2; ++h) {        // two K=32 halves
            int kc = h * 4 + l4;
            bf16x8 af[4], bfr[6];
#pragma unroll
            for (int mi = 0; mi < 4; ++mi) {
                int r = wm * 64 + mi * 16 + l15;
                uint4 t = As4[r * 8 + (kc ^ (r & 7))];
                af[mi] = *(bf16x8*)&t;
            }
#pragma unroll
            for (int g = 0; g < 3; ++g)
#pragma unroll
                for (int t2 = 0; t2 < 2; ++t2) {
                    int cc = g * 128 + wn * 32 + t2 * 16 + l15;
                    uint4 t = Bs4[cc * 8 + (kc ^ (cc & 7))];
                    bfr[g * 2 + t2] = *(bf16x8*)&t;
                }
#pragma unroll
            for (int mi = 0; mi < 4; ++mi)
#pragma unroll
                for (int nj = 0; nj < 6; ++nj)
                    acc[mi][nj] = __builtin_amdgcn_mfma_f32_16x16x32_bf16(
                        af[mi], bfr[nj], acc[mi][nj], 0, 0, 0);
        }
        __syncthreads();
    }
    // epilogue: D col = lane&15, row = (lane>>4)*4 + reg  [m89/m91]
#pragma unroll
    for (int mi = 0; mi < 4; ++mi) {
#pragma unroll
        for (int rg = 0; rg < 4; ++rg) {
            int row = m0 + wm * 64 + mi * 16 + l4 * 4 + rg;
            if (row >= N_NODES) continue;
            float am = amp[row], at = att[row];
#pragma unroll
            for (int t2 = 0; t2 < 2; ++t2) {
                int c = wn * 32 + t2 * 16 + l15;
                float v = acc[mi][t2][rg] + am * acc[mi][2 + t2][rg]
                        + at * acc[mi][4 + t2][rg] + bias[c];
                out[(size_t)row * DIM + c] = v;
            }
        }
    }
}

__global__ void k_user(const int* __restrict__ user_idx, const float* __restrict__ htilde,
                       float* __restrict__ h_user) {
    int t = blockIdx.x * blockDim.x + threadIdx.x;
    if (t < BATCH * DIM) {
        int b = t >> 7, d = t & 127;
        int idx = user_idx[b];
        if (idx == 0x7FFFFFFF) idx = 0;
        h_user[t] = htilde[(size_t)idx * DIM + d];
    }
}

__global__ __launch_bounds__(256) void k_score(
    const float* __restrict__ h_user, const int* __restrict__ nodes,
    const float* __restrict__ Wsc, const float* __restrict__ bsc,
    float* __restrict__ out)
{
    int wid = (blockIdx.x * blockDim.x + threadIdx.x) >> 6;
    int lane = threadIdx.x & 63;
    if (wid >= N_NODES) return;
    int b = nodes[2 * wid];
    float2 hu = *(const float2*)&h_user[b * DIM + lane * 2];
    float2 ht = *(const float2*)&out[(size_t)wid * DIM + lane * 2];
    float2 w0 = *(const float2*)&Wsc[lane * 2];
    float2 w1 = *(const float2*)&Wsc[DIM + lane * 2];
    float p = hu.x * w0.x + hu.y * w0.y + ht.x * w1.x + ht.y * w1.y;
#pragma unroll
    for (int off = 32; off; off >>= 1) p += __shfl_xor(p, off);
    float alpha = 1.f / (1.f + expf(-(p + bsc[0])));
    float2 o = make_float2(alpha * ht.x, alpha * ht.y);
    *(float2*)&out[(size_t)wid * DIM + lane * 2] = o;
}

extern "C" void kernel_launch(void* const* d_in, const int* in_sizes, int n_in,
                              void* d_out, int out_size, void* d_ws, size_t ws_size,
                              hipStream_t stream)
{
    const float* hidden = (const float*)d_in[0];
    const float* rela   = (const float*)d_in[1];
    const float* W_agg  = (const float*)d_in[2];
    const float* b_agg  = (const float*)d_in[3];
    const float* W_sc   = (const float*)d_in[4];
    const float* b_sc   = (const float*)d_in[5];
    const int* edges    = (const int*)d_in[6];
    const int* nodes    = (const int*)d_in[7];
    const int* q_sub    = (const int*)d_in[8];
    const int* old_idx  = (const int*)d_in[9];
    float* out = (float*)d_out;

    char* p = (char*)d_ws;
    auto carve = [&](size_t bytes) { char* r = p; p += (bytes + 255) & ~255ULL; return r; };
    unsigned short* Ap  = (unsigned short*)carve((size_t)N_NODES * KA * 2);  // 128 MB
    unsigned short* Wtb = (unsigned short*)carve((size_t)NB * KA * 2);       // 0.5 MB
    int4*  recs    = (int4*) carve((size_t)N_EDGES * 16);                    // 16 MB
    float* P       = (float*)carve((size_t)N_PREV * N_REL * 4);              // 13.8 MB
    float* hnorm2  = (float*)carve((size_t)N_PREV * 4);
    float* rnorm2  = (float*)carve(N_REL * 4);
    int*   cnt     = (int*)  carve((size_t)N_NODES * 4);
    int*   offsets = (int*)  carve(((size_t)N_NODES + 1) * 4);
    int*   cursor  = (int*)  carve((size_t)N_NODES * 4);
    int*   inv     = (int*)  carve((size_t)N_NODES * 4);
    float* amp     = (float*)carve((size_t)N_NODES * 4);
    float* att     = (float*)carve((size_t)N_NODES * 4);
    int*   user_idx = (int*) carve(BATCH * 4);
    float* h_user   = (float*)carve(BATCH * DIM * 4);

    k_setup<<<(N_NODES + 255) / 256, 256, 0, stream>>>(cnt, inv, user_idx);
    k_scatter<<<(N_NODES + 255) / 256, 256, 0, stream>>>(old_idx, nodes, q_sub, inv, user_idx);
    k_count<<<(N_EDGES + 255) / 256, 256, 0, stream>>>(edges, cnt);
    k_convW<<<(NB * KA + 255) / 256, 256, 0, stream>>>(W_agg, Wtb);
    k_norms<<<(N_PREV + N_REL + 3) / 4, 256, 0, stream>>>(hidden, rela, hnorm2, rnorm2);
    k_dotP<<<(N_PREV + 3) / 4, 256, 0, stream>>>(hidden, rela, P);
    k_scan<<<1, 1024, 0, stream>>>(cnt, offsets, cursor);
    k_msg<<<(N_EDGES + 255) / 256, 256, 0, stream>>>(edges, P, hnorm2, rnorm2, cursor, recs);
    k_agg<<<(N_NODES + 3) / 4, 256, 0, stream>>>(hidden, rela, recs, offsets, inv, Ap, amp, att);
    k_gemm_mfma<<<(N_NODES + 127) / 128, 512, 0, stream>>>(Ap, Wtb, amp, att, b_agg, out);
    k_user<<<4, 256, 0, stream>>>(user_idx, out, h_user);
    k_score<<<(N_NODES * 64 + 255) / 256, 256, 0, stream>>>(h_user, nodes, W_sc, b_sc, out);
}

// Round 12
// 708.624 us; speedup vs baseline: 5.9357x; 1.3568x over previous
//
#include <hip/hip_runtime.h>
#include <math.h>

#define N_NODES 100000
#define N_PREV  80000
#define N_EDGES 1000000
#define N_REL   43
#define DIM     128
#define BATCH   8
#define KA      640    // A' width: 512 agg + 128 h_prev
#define NB      384    // B' cols: 3 groups x 128
#define SCAN_CHUNK 1024                 // elems per block in scan
#define SCAN_NBLK ((N_NODES + SCAN_CHUNK - 1) / SCAN_CHUNK)   // 98

typedef __attribute__((ext_vector_type(8))) short bf16x8;
typedef __attribute__((ext_vector_type(4))) float f32x4;

// f32 -> bf16 round-to-nearest-even (finite inputs)
__device__ __forceinline__ unsigned short f2bf(float f) {
    unsigned u = __float_as_uint(f);
    unsigned r = (u + 0x7FFFu + ((u >> 16) & 1u)) >> 16;
    return (unsigned short)r;
}
__device__ __forceinline__ void st_bf2(unsigned short* p, float a, float b) {
    *(unsigned*)p = (unsigned)f2bf(a) | ((unsigned)f2bf(b) << 16);
}

__global__ void k_setup(int* __restrict__ cnt, int* __restrict__ inv,
                        int* __restrict__ user_idx) {
    int i = blockIdx.x * blockDim.x + threadIdx.x;
    if (i < N_NODES) { cnt[i] = 0; inv[i] = -1; }
    if (i < BATCH) user_idx[i] = 0x7FFFFFFF;
}

__global__ void k_scatter(const int* __restrict__ old_idx, const int* __restrict__ nodes,
                          const int* __restrict__ q_sub, int* __restrict__ inv,
                          int* __restrict__ user_idx) {
    int i = blockIdx.x * blockDim.x + threadIdx.x;
    if (i < N_PREV) inv[old_idx[i]] = i;
    if (i < N_NODES) {
        int b = nodes[2 * i], e = nodes[2 * i + 1];
        if (b >= 0 && b < BATCH && q_sub[b] == e) atomicMin(&user_idx[b], i);
    }
}

__global__ void k_count(const int* __restrict__ edges, int* __restrict__ cnt) {
    int i = blockIdx.x * blockDim.x + threadIdx.x;
    if (i < N_EDGES) atomicAdd(&cnt[edges[i * 6 + 5]], 1);
}

// Build B' bf16 [NB][KA]:  c' = g*128+c.  k<512: W[(g*512+k)][c];  k>=512: g==0 ? W[1536+k-512][c] : 0
__global__ void k_convW(const float* __restrict__ W, unsigned short* __restrict__ Wt) {
    int i = blockIdx.x * blockDim.x + threadIdx.x;
    if (i >= NB * KA) return;
    int cp = i / KA, kp = i - cp * KA;
    int g = cp >> 7, c = cp & 127;
    float v;
    if (kp < 512) v = W[(size_t)(g * 512 + kp) * DIM + c];
    else          v = (g == 0) ? W[(size_t)(1536 + kp - 512) * DIM + c] : 0.f;
    Wt[(size_t)cp * KA + kp] = f2bf(v);
}

// squared norms of hidden rows and rela rows
__global__ __launch_bounds__(256) void k_norms(const float* __restrict__ hidden,
                                               const float* __restrict__ rela,
                                               float* __restrict__ hnorm2,
                                               float* __restrict__ rnorm2) {
    int wid = (blockIdx.x * blockDim.x + threadIdx.x) >> 6;
    int lane = threadIdx.x & 63;
    if (wid >= N_PREV + N_REL) return;
    const float* src = (wid < N_PREV) ? &hidden[(size_t)wid * DIM]
                                      : &rela[(size_t)(wid - N_PREV) * DIM];
    float2 v = *(const float2*)&src[lane * 2];
    float p = v.x * v.x + v.y * v.y;
#pragma unroll
    for (int off = 32; off; off >>= 1) p += __shfl_xor(p, off);
    if (lane == 0) {
        if (wid < N_PREV) hnorm2[wid] = p;
        else rnorm2[wid - N_PREV] = p;
    }
}

// P[sub][rel] = hidden[sub] . rela[rel]  (wave per sub row; hidden read once)
__global__ __launch_bounds__(256) void k_dotP(
    const float* __restrict__ hidden, const float* __restrict__ rela,
    float* __restrict__ P)
{
    int wid = (blockIdx.x * blockDim.x + threadIdx.x) >> 6;
    int lane = threadIdx.x & 63;
    if (wid >= N_PREV) return;
    float2 h = *(const float2*)&hidden[(size_t)wid * DIM + lane * 2];
    for (int r = 0; r < N_REL; ++r) {
        float2 v = *(const float2*)&rela[r * DIM + lane * 2];
        float p = h.x * v.x + h.y * v.y;
#pragma unroll
        for (int off = 32; off; off >>= 1) p += __shfl_xor(p, off);
        if (lane == 0) P[(size_t)wid * N_REL + r] = p;
    }
}

// ---- 3-pass hierarchical scan of cnt[N_NODES] ----
// pass 1: per-block (1024 elems) local exclusive scan -> offsets; block total -> bsum
__global__ __launch_bounds__(256) void k_scan1(const int* __restrict__ cnt,
                                               int* __restrict__ offsets,
                                               int* __restrict__ bsum) {
    __shared__ int wsum[4];
    int tid = threadIdx.x;
    int lane = tid & 63, wave = tid >> 6;
    int base = blockIdx.x * SCAN_CHUNK + tid * 4;
    int a0 = 0, a1 = 0, a2 = 0, a3 = 0;
    if (base + 3 < N_NODES) {
        int4 v = *(const int4*)&cnt[base];
        a0 = v.x; a1 = v.y; a2 = v.z; a3 = v.w;
    } else {
        if (base + 0 < N_NODES) a0 = cnt[base + 0];
        if (base + 1 < N_NODES) a1 = cnt[base + 1];
        if (base + 2 < N_NODES) a2 = cnt[base + 2];
        if (base + 3 < N_NODES) a3 = cnt[base + 3];
    }
    int s = a0 + a1 + a2 + a3;
    int inc = s;
#pragma unroll
    for (int off = 1; off < 64; off <<= 1) {
        int n = __shfl_up(inc, off);
        if (lane >= off) inc += n;
    }
    if (lane == 63) wsum[wave] = inc;
    __syncthreads();
    int wbase = 0;
#pragma unroll
    for (int w = 0; w < 4; ++w) wbase += (w < wave) ? wsum[w] : 0;
    int excl = wbase + inc - s;   // exclusive prefix within block
    if (base < N_NODES) {
        int e0 = excl, e1 = e0 + a0, e2 = e1 + a1, e3 = e2 + a2;
        if (base + 3 < N_NODES) {
            *(int4*)&offsets[base] = make_int4(e0, e1, e2, e3);
        } else {
            if (base + 0 < N_NODES) offsets[base + 0] = e0;
            if (base + 1 < N_NODES) offsets[base + 1] = e1;
            if (base + 2 < N_NODES) offsets[base + 2] = e2;
        }
    }
    if (tid == 255) bsum[blockIdx.x] = wbase + inc;   // block total (tid255 has full)
}

// pass 2: one block scans the 98 block totals (exclusive, in place)
__global__ __launch_bounds__(128) void k_scan2(int* __restrict__ bsum) {
    __shared__ int sh[SCAN_NBLK];
    int tid = threadIdx.x;
    if (tid < SCAN_NBLK) sh[tid] = bsum[tid];
    __syncthreads();
    if (tid == 0) {
        int run = 0;
        for (int i = 0; i < SCAN_NBLK; ++i) { int v = sh[i]; sh[i] = run; run += v; }
    }
    __syncthreads();
    if (tid < SCAN_NBLK) bsum[tid] = sh[tid];
}

// pass 3: add block base; mirror into cursor; set offsets[N_NODES]
__global__ __launch_bounds__(256) void k_scan3(int* __restrict__ offsets,
                                               int* __restrict__ cursor,
                                               const int* __restrict__ bsum) {
    int base = blockIdx.x * SCAN_CHUNK + threadIdx.x * 4;
    int bb = bsum[blockIdx.x];
    if (base + 3 < N_NODES) {
        int4 v = *(const int4*)&offsets[base];
        v.x += bb; v.y += bb; v.z += bb; v.w += bb;
        *(int4*)&offsets[base] = v;
        *(int4*)&cursor[base] = v;
    } else {
        for (int j = 0; j < 4; ++j) {
            int idx = base + j;
            if (idx < N_NODES) { int v = offsets[idx] + bb; offsets[idx] = v; cursor[idx] = v; }
        }
    }
    if (blockIdx.x == 0 && threadIdx.x == 0) offsets[N_NODES] = N_EDGES;
}

// ONE THREAD per edge: pc gathered from P table; scalar hyperbolic math; scatter record
__global__ __launch_bounds__(256) void k_msg(
    const int* __restrict__ edges, const float* __restrict__ P,
    const float* __restrict__ hnorm2, const float* __restrict__ rnorm2,
    int* __restrict__ cursor, int4* __restrict__ recs)
{
    int i = blockIdx.x * blockDim.x + threadIdx.x;
    if (i >= N_EDGES) return;
    int rel = edges[i * 6 + 2];
    int sub = edges[i * 6 + 4];
    int obj = edges[i * 6 + 5];

    float pc = P[(size_t)sub * N_REL + rel];
    float ps = hnorm2[sub];
    float pr = rnorm2[rel];

    const float MAXN = 0.996f;   // (1-EPS_BALL)/sqrt(C)
    float ns = fmaxf(sqrtf(ps), 1e-15f);
    float cs = fminf(tanhf(fminf(ns, 15.f)), MAXN);
    float sx = cs / ns;
    float x2 = cs * cs;
    float nr = fmaxf(sqrtf(pr), 1e-15f);
    float cr = fminf(tanhf(fminf(nr, 15.f)), MAXN);
    float sy = cr / nr;
    float y2 = cr * cr;
    float xy = pc * sx * sy;
    float ca = 1.f + 2.f * xy + y2;
    float cb = 1.f - x2;
    float den = fmaxf(1.f + 2.f * xy + x2 * y2, 1e-15f);
    float id = 1.f / den;
    float pm = fmaxf((ca * ca * x2 + 2.f * ca * cb * xy + cb * cb * y2) * id * id, 0.f);
    float nm = fmaxf(sqrtf(pm), 1e-15f);
    float a  = atanhf(fminf(nm, MAXN));
    float sc = a / nm;
    float alpha = sc * id * ca * sx;
    float beta  = sc * id * cb * sy;

    int pos = atomicAdd(&cursor[obj], 1);
    recs[pos] = make_int4(sub, rel, __float_as_int(alpha), __float_as_int(beta));
}

// wave per node: walk sorted records; write A' row [mean,mx,mn,sd(512) | h_prev(128)] bf16 + amp/att
__global__ __launch_bounds__(256) void k_agg(
    const float* __restrict__ hidden, const float* __restrict__ rela,
    const int4* __restrict__ recs, const int* __restrict__ offsets,
    const int* __restrict__ inv, unsigned short* __restrict__ Ap,
    float* __restrict__ amp, float* __restrict__ att)
{
    int node = blockIdx.x * 4 + (threadIdx.x >> 6);
    int lane = threadIdx.x & 63;
    if (node >= N_NODES) return;
    int beg = offsets[node], end = offsets[node + 1];
    float s0 = 0.f, s1 = 0.f, q0 = 0.f, q1 = 0.f;
    float mx0 = -INFINITY, mx1 = -INFINITY, mn0 = INFINITY, mn1 = INFINITY;
    for (int e = beg; e < end; ++e) {
        int4 rc = recs[e];
        float al = __int_as_float(rc.z), be = __int_as_float(rc.w);
        float2 u = *(const float2*)&hidden[rc.x * DIM + lane * 2];
        float2 r = *(const float2*)&rela[rc.y * DIM + lane * 2];
        float m0 = al * u.x + be * r.x;
        float m1 = al * u.y + be * r.y;
        s0 += m0; s1 += m1;
        q0 = fmaf(m0, m0, q0); q1 = fmaf(m1, m1, q1);
        mx0 = fmaxf(mx0, m0); mx1 = fmaxf(mx1, m1);
        mn0 = fminf(mn0, m0); mn1 = fminf(mn1, m1);
    }
    float d  = (float)(end - beg);
    float d1 = fmaxf(d, 1.f);
    float me0 = s0 / d1, me1 = s1 / d1;
    float sd0 = sqrtf(fmaxf(q0 / d1 - me0 * me0, 0.f) + 1e-10f);
    float sd1 = sqrtf(fmaxf(q1 / d1 - me1 * me1, 0.f) + 1e-10f);
    if (!(d > 0.f)) { mx0 = mx1 = mn0 = mn1 = 0.f; }

    unsigned short* row = Ap + (size_t)node * KA;
    int o = lane * 2;
    st_bf2(row +   0 + o, me0, me1);
    st_bf2(row + 128 + o, mx0, mx1);
    st_bf2(row + 256 + o, mn0, mn1);
    st_bf2(row + 384 + o, sd0, sd1);
    int ii = inv[node];
    float h0 = 0.f, h1 = 0.f;
    if (ii >= 0) {
        float2 h = *(const float2*)&hidden[(size_t)ii * DIM + o];
        h0 = h.x; h1 = h.y;
    }
    st_bf2(row + 512 + o, h0, h1);
    if (lane == 0) {
        float logd = log1pf(d);
        amp[node] = logd;                       // logd / PNA_DELTA
        att[node] = 1.f / fmaxf(logd, 1e-5f);   // PNA_DELTA / max(logd,1e-5)
    }
}

// C[100000][384] = A'[100000][640] @ B'^T[384][640]; fused combine:
// out[n][c] = C[n][c] + amp[n]*C[n][128+c] + att[n]*C[n][256+c] + bias[c]
// 512 thr = 8 waves (2m x 4n); block tile 128x384; wave tile 64 rows x {32 cols x 3 groups}
__global__ __launch_bounds__(512) void k_gemm_mfma(
    const unsigned short* __restrict__ Ap,   // [N_NODES][KA]
    const unsigned short* __restrict__ Wt,   // [NB][KA]
    const float* __restrict__ amp, const float* __restrict__ att,
    const float* __restrict__ bias, float* __restrict__ out)
{
    __shared__ uint4 As4[128 * 8];   // [row][chunk ^ (row&7)]
    __shared__ uint4 Bs4[NB * 8];    // [col'][chunk ^ (col'&7)]
    int tid = threadIdx.x;
    int wave = tid >> 6, lane = tid & 63;
    int wm = wave >> 2, wn = wave & 3;       // 2 x 4
    int l15 = lane & 15, l4 = lane >> 4;
    int m0 = blockIdx.x * 128;

    f32x4 acc[4][6];                         // [mi][g*2+t]
#pragma unroll
    for (int mi = 0; mi < 4; ++mi)
#pragma unroll
        for (int nj = 0; nj < 6; ++nj) acc[mi][nj] = (f32x4){0.f, 0.f, 0.f, 0.f};

    for (int k0 = 0; k0 < KA; k0 += 64) {
#pragma unroll
        for (int it = 0; it < 2; ++it) {     // A: 1024 chunks
            int c = tid + it * 512;
            int row = c >> 3, ko = c & 7;
            int gr = m0 + row; if (gr >= N_NODES) gr = N_NODES - 1;
            As4[row * 8 + (ko ^ (row & 7))] =
                *((const uint4*)(Ap + (size_t)gr * KA + k0) + ko);
        }
#pragma unroll
        for (int it = 0; it < 6; ++it) {     // B: 3072 chunks
            int c = tid + it * 512;
            int row = c >> 3, ko = c & 7;
            Bs4[row * 8 + (ko ^ (row & 7))] =
                *((const uint4*)(Wt + (size_t)row * KA + k0) + ko);
        }
        __syncthreads();
#pragma unroll
        for (int h = 0; h < 2; ++h) {        // two K=32 halves
            int kc = h * 4 + l4;
            bf16x8 af[4], bfr[6];
#pragma unroll
            for (int mi = 0; mi < 4; ++mi) {
                int r = wm * 64 + mi * 16 + l15;
                uint4 t = As4[r * 8 + (kc ^ (r & 7))];
                af[mi] = *(bf16x8*)&t;
            }
#pragma unroll
            for (int g = 0; g < 3; ++g)
#pragma unroll
                for (int t2 = 0; t2 < 2; ++t2) {
                    int cc = g * 128 + wn * 32 + t2 * 16 + l15;
                    uint4 t = Bs4[cc * 8 + (kc ^ (cc & 7))];
                    bfr[g * 2 + t2] = *(bf16x8*)&t;
                }
#pragma unroll
            for (int mi = 0; mi < 4; ++mi)
#pragma unroll
                for (int nj = 0; nj < 6; ++nj)
                    acc[mi][nj] = __builtin_amdgcn_mfma_f32_16x16x32_bf16(
                        af[mi], bfr[nj], acc[mi][nj], 0, 0, 0);
        }
        __syncthreads();
    }
    // epilogue: D col = lane&15, row = (lane>>4)*4 + reg  [m89/m91]
#pragma unroll
    for (int mi = 0; mi < 4; ++mi) {
#pragma unroll
        for (int rg = 0; rg < 4; ++rg) {
            int row = m0 + wm * 64 + mi * 16 + l4 * 4 + rg;
            if (row >= N_NODES) continue;
            float am = amp[row], at = att[row];
#pragma unroll
            for (int t2 = 0; t2 < 2; ++t2) {
                int c = wn * 32 + t2 * 16 + l15;
                float v = acc[mi][t2][rg] + am * acc[mi][2 + t2][rg]
                        + at * acc[mi][4 + t2][rg] + bias[c];
                out[(size_t)row * DIM + c] = v;
            }
        }
    }
}

__global__ void k_user(const int* __restrict__ user_idx, const float* __restrict__ htilde,
                       float* __restrict__ h_user) {
    int t = blockIdx.x * blockDim.x + threadIdx.x;
    if (t < BATCH * DIM) {
        int b = t >> 7, d = t & 127;
        int idx = user_idx[b];
        if (idx == 0x7FFFFFFF) idx = 0;
        h_user[t] = htilde[(size_t)idx * DIM + d];
    }
}

__global__ __launch_bounds__(256) void k_score(
    const float* __restrict__ h_user, const int* __restrict__ nodes,
    const float* __restrict__ Wsc, const float* __restrict__ bsc,
    float* __restrict__ out)
{
    int wid = (blockIdx.x * blockDim.x + threadIdx.x) >> 6;
    int lane = threadIdx.x & 63;
    if (wid >= N_NODES) return;
    int b = nodes[2 * wid];
    float2 hu = *(const float2*)&h_user[b * DIM + lane * 2];
    float2 ht = *(const float2*)&out[(size_t)wid * DIM + lane * 2];
    float2 w0 = *(const float2*)&Wsc[lane * 2];
    float2 w1 = *(const float2*)&Wsc[DIM + lane * 2];
    float p = hu.x * w0.x + hu.y * w0.y + ht.x * w1.x + ht.y * w1.y;
#pragma unroll
    for (int off = 32; off; off >>= 1) p += __shfl_xor(p, off);
    float alpha = 1.f / (1.f + expf(-(p + bsc[0])));
    float2 o = make_float2(alpha * ht.x, alpha * ht.y);
    *(float2*)&out[(size_t)wid * DIM + lane * 2] = o;
}

extern "C" void kernel_launch(void* const* d_in, const int* in_sizes, int n_in,
                              void* d_out, int out_size, void* d_ws, size_t ws_size,
                              hipStream_t stream)
{
    const float* hidden = (const float*)d_in[0];
    const float* rela   = (const float*)d_in[1];
    const float* W_agg  = (const float*)d_in[2];
    const float* b_agg  = (const float*)d_in[3];
    const float* W_sc   = (const float*)d_in[4];
    const float* b_sc   = (const float*)d_in[5];
    const int* edges    = (const int*)d_in[6];
    const int* nodes    = (const int*)d_in[7];
    const int* q_sub    = (const int*)d_in[8];
    const int* old_idx  = (const int*)d_in[9];
    float* out = (float*)d_out;

    char* p = (char*)d_ws;
    auto carve = [&](size_t bytes) { char* r = p; p += (bytes + 255) & ~255ULL; return r; };
    unsigned short* Ap  = (unsigned short*)carve((size_t)N_NODES * KA * 2);  // 128 MB
    unsigned short* Wtb = (unsigned short*)carve((size_t)NB * KA * 2);       // 0.5 MB
    int4*  recs    = (int4*) carve((size_t)N_EDGES * 16);                    // 16 MB
    float* P       = (float*)carve((size_t)N_PREV * N_REL * 4);              // 13.8 MB
    float* hnorm2  = (float*)carve((size_t)N_PREV * 4);
    float* rnorm2  = (float*)carve(N_REL * 4);
    int*   cnt     = (int*)  carve((size_t)N_NODES * 4);
    int*   offsets = (int*)  carve(((size_t)N_NODES + 1) * 4);
    int*   cursor  = (int*)  carve((size_t)N_NODES * 4);
    int*   inv     = (int*)  carve((size_t)N_NODES * 4);
    float* amp     = (float*)carve((size_t)N_NODES * 4);
    float* att     = (float*)carve((size_t)N_NODES * 4);
    int*   bsum    = (int*)  carve(SCAN_NBLK * 4);
    int*   user_idx = (int*) carve(BATCH * 4);
    float* h_user   = (float*)carve(BATCH * DIM * 4);

    k_setup<<<(N_NODES + 255) / 256, 256, 0, stream>>>(cnt, inv, user_idx);
    k_scatter<<<(N_NODES + 255) / 256, 256, 0, stream>>>(old_idx, nodes, q_sub, inv, user_idx);
    k_count<<<(N_EDGES + 255) / 256, 256, 0, stream>>>(edges, cnt);
    k_convW<<<(NB * KA + 255) / 256, 256, 0, stream>>>(W_agg, Wtb);
    k_norms<<<(N_PREV + N_REL + 3) / 4, 256, 0, stream>>>(hidden, rela, hnorm2, rnorm2);
    k_dotP<<<(N_PREV + 3) / 4, 256, 0, stream>>>(hidden, rela, P);
    k_scan1<<<SCAN_NBLK, 256, 0, stream>>>(cnt, offsets, bsum);
    k_scan2<<<1, 128, 0, stream>>>(bsum);
    k_scan3<<<SCAN_NBLK, 256, 0, stream>>>(offsets, cursor, bsum);
    k_msg<<<(N_EDGES + 255) / 256, 256, 0, stream>>>(edges, P, hnorm2, rnorm2, cursor, recs);
    k_agg<<<(N_NODES + 3) / 4, 256, 0, stream>>>(hidden, rela, recs, offsets, inv, Ap, amp, att);
    k_gemm_mfma<<<(N_NODES + 127) / 128, 512, 0, stream>>>(Ap, Wtb, amp, att, b_agg, out);
    k_user<<<4, 256, 0, stream>>>(user_idx, out, h_user);
    k_score<<<(N_NODES * 64 + 255) / 256, 256, 0, stream>>>(h_user, nodes, W_sc, b_sc, out);
}

// Round 14
// 508.715 us; speedup vs baseline: 8.2682x; 1.3930x over previous
//
#include <hip/hip_runtime.h>
#include <math.h>

#define N_NODES 100000
#define N_PREV  80000
#define N_EDGES 1000000
#define N_REL   43
#define DIM     128
#define BATCH   8
#define KA      640    // A' width: 512 agg + 128 h_prev
#define NB      384    // B' cols: 3 groups x 128
#define SCAN_CHUNK 1024
#define SCAN_NBLK ((N_NODES + SCAN_CHUNK - 1) / SCAN_CHUNK)   // 98

typedef __attribute__((ext_vector_type(8))) short bf16x8;
typedef __attribute__((ext_vector_type(4))) float f32x4;

// f32 -> bf16 round-to-nearest-even (finite inputs)
__device__ __forceinline__ unsigned short f2bf(float f) {
    unsigned u = __float_as_uint(f);
    unsigned r = (u + 0x7FFFu + ((u >> 16) & 1u)) >> 16;
    return (unsigned short)r;
}
__device__ __forceinline__ void st_bf2(unsigned short* p, float a, float b) {
    *(unsigned*)p = (unsigned)f2bf(a) | ((unsigned)f2bf(b) << 16);
}

__global__ void k_setup(int* __restrict__ cnt, int* __restrict__ inv,
                        int* __restrict__ user_idx) {
    int i = blockIdx.x * blockDim.x + threadIdx.x;
    if (i < N_NODES) { cnt[i] = 0; inv[i] = -1; }
    if (i < BATCH) user_idx[i] = 0x7FFFFFFF;
}

__global__ void k_scatter(const int* __restrict__ old_idx, const int* __restrict__ nodes,
                          const int* __restrict__ q_sub, int* __restrict__ inv,
                          int* __restrict__ user_idx) {
    int i = blockIdx.x * blockDim.x + threadIdx.x;
    if (i < N_PREV) inv[old_idx[i]] = i;
    if (i < N_NODES) {
        int b = nodes[2 * i], e = nodes[2 * i + 1];
        if (b >= 0 && b < BATCH && q_sub[b] == e) atomicMin(&user_idx[b], i);
    }
}

__global__ void k_count(const int* __restrict__ edges, int* __restrict__ cnt) {
    int i = blockIdx.x * blockDim.x + threadIdx.x;
    if (i < N_EDGES) atomicAdd(&cnt[edges[i * 6 + 5]], 1);
}

// Build B' bf16 [NB][KA]
__global__ void k_convW(const float* __restrict__ W, unsigned short* __restrict__ Wt) {
    int i = blockIdx.x * blockDim.x + threadIdx.x;
    if (i >= NB * KA) return;
    int cp = i / KA, kp = i - cp * KA;
    int g = cp >> 7, c = cp & 127;
    float v;
    if (kp < 512) v = W[(size_t)(g * 512 + kp) * DIM + c];
    else          v = (g == 0) ? W[(size_t)(1536 + kp - 512) * DIM + c] : 0.f;
    Wt[(size_t)cp * KA + kp] = f2bf(v);
}

// hidden f32 -> bf16 (4 elems/thread)
__global__ void k_convH(const float* __restrict__ hidden, unsigned short* __restrict__ hb) {
    int i = blockIdx.x * blockDim.x + threadIdx.x;
    if (i >= N_PREV * DIM / 4) return;
    float4 v = *(const float4*)&hidden[(size_t)i * 4];
    unsigned short* p = hb + (size_t)i * 4;
    st_bf2(p, v.x, v.y);
    st_bf2(p + 2, v.z, v.w);
}

// rela f32 -> bf16 padded to 48 rows
__global__ void k_convR(const float* __restrict__ rela, unsigned short* __restrict__ rb) {
    int i = blockIdx.x * blockDim.x + threadIdx.x;
    if (i >= 48 * DIM) return;
    int r = i >> 7, c = i & 127;
    float v = (r < N_REL) ? rela[(size_t)r * DIM + c] : 0.f;
    rb[i] = f2bf(v);
}

// squared norms of hidden rows and rela rows (f32, exact)
__global__ __launch_bounds__(256) void k_norms(const float* __restrict__ hidden,
                                               const float* __restrict__ rela,
                                               float* __restrict__ hnorm2,
                                               float* __restrict__ rnorm2) {
    int wid = (blockIdx.x * blockDim.x + threadIdx.x) >> 6;
    int lane = threadIdx.x & 63;
    if (wid >= N_PREV + N_REL) return;
    const float* src = (wid < N_PREV) ? &hidden[(size_t)wid * DIM]
                                      : &rela[(size_t)(wid - N_PREV) * DIM];
    float2 v = *(const float2*)&src[lane * 2];
    float p = v.x * v.x + v.y * v.y;
#pragma unroll
    for (int off = 32; off; off >>= 1) p += __shfl_xor(p, off);
    if (lane == 0) {
        if (wid < N_PREV) hnorm2[wid] = p;
        else rnorm2[wid - N_PREV] = p;
    }
}

// P[sub][rel] = hidden[sub].rela[rel] via bf16 MFMA: M=80000, N=48(pad), K=128
// block: 64 rows, 4 waves (16 rows each), 3 col-tiles of 16
__global__ __launch_bounds__(256) void k_dotP(
    const unsigned short* __restrict__ hiddenB,  // [N_PREV][128] bf16
    const unsigned short* __restrict__ relaB,    // [48][128] bf16
    float* __restrict__ P)                       // [N_PREV][43]
{
    __shared__ uint4 Hs[64 * 16];   // [row][chunk ^ (row&15)]
    __shared__ uint4 Rs[48 * 16];
    int tid = threadIdx.x;
    int wave = tid >> 6, lane = tid & 63;
    int l15 = lane & 15, l4 = lane >> 4;
    int m0 = blockIdx.x * 64;

#pragma unroll
    for (int it = 0; it < 4; ++it) {            // 1024 chunks of hidden tile
        int c = tid + it * 256;
        int row = c >> 4, ko = c & 15;
        Hs[row * 16 + (ko ^ (row & 15))] =
            *((const uint4*)(hiddenB + (size_t)(m0 + row) * DIM) + ko);
    }
#pragma unroll
    for (int it = 0; it < 3; ++it) {            // 768 chunks of rela tile
        int c = tid + it * 256;
        int row = c >> 4, ko = c & 15;
        Rs[row * 16 + (ko ^ (row & 15))] =
            *((const uint4*)(relaB + (size_t)row * DIM) + ko);
    }
    __syncthreads();

    f32x4 acc[3];
    acc[0] = (f32x4){0.f, 0.f, 0.f, 0.f};
    acc[1] = acc[0]; acc[2] = acc[0];
#pragma unroll
    for (int ks = 0; ks < 4; ++ks) {
        int kc = ks * 4 + l4;
        int r = wave * 16 + l15;
        uint4 ta = Hs[r * 16 + (kc ^ (r & 15))];
        bf16x8 af = *(bf16x8*)&ta;
#pragma unroll
        for (int g = 0; g < 3; ++g) {
            int cc = g * 16 + l15;
            uint4 tb = Rs[cc * 16 + (kc ^ (cc & 15))];
            bf16x8 bfr = *(bf16x8*)&tb;
            acc[g] = __builtin_amdgcn_mfma_f32_16x16x32_bf16(af, bfr, acc[g], 0, 0, 0);
        }
    }
    // C: col = lane&15, row = (lane>>4)*4 + reg  [m89/m91]
#pragma unroll
    for (int g = 0; g < 3; ++g) {
        int col = g * 16 + l15;
        if (col < N_REL) {
#pragma unroll
            for (int rg = 0; rg < 4; ++rg) {
                int row = m0 + wave * 16 + l4 * 4 + rg;
                P[(size_t)row * N_REL + col] = acc[g][rg];
            }
        }
    }
}

// ---- 3-pass hierarchical scan ----
__global__ __launch_bounds__(256) void k_scan1(const int* __restrict__ cnt,
                                               int* __restrict__ offsets,
                                               int* __restrict__ bsum) {
    __shared__ int wsum[4];
    int tid = threadIdx.x;
    int lane = tid & 63, wave = tid >> 6;
    int base = blockIdx.x * SCAN_CHUNK + tid * 4;
    int a0 = 0, a1 = 0, a2 = 0, a3 = 0;
    if (base + 3 < N_NODES) {
        int4 v = *(const int4*)&cnt[base];
        a0 = v.x; a1 = v.y; a2 = v.z; a3 = v.w;
    } else {
        if (base + 0 < N_NODES) a0 = cnt[base + 0];
        if (base + 1 < N_NODES) a1 = cnt[base + 1];
        if (base + 2 < N_NODES) a2 = cnt[base + 2];
        if (base + 3 < N_NODES) a3 = cnt[base + 3];
    }
    int s = a0 + a1 + a2 + a3;
    int inc = s;
#pragma unroll
    for (int off = 1; off < 64; off <<= 1) {
        int n = __shfl_up(inc, off);
        if (lane >= off) inc += n;
    }
    if (lane == 63) wsum[wave] = inc;
    __syncthreads();
    int wbase = 0;
#pragma unroll
    for (int w = 0; w < 4; ++w) wbase += (w < wave) ? wsum[w] : 0;
    int excl = wbase + inc - s;
    if (base < N_NODES) {
        int e0 = excl, e1 = e0 + a0, e2 = e1 + a1, e3 = e2 + a2;
        if (base + 3 < N_NODES) {
            *(int4*)&offsets[base] = make_int4(e0, e1, e2, e3);
        } else {
            if (base + 0 < N_NODES) offsets[base + 0] = e0;
            if (base + 1 < N_NODES) offsets[base + 1] = e1;
            if (base + 2 < N_NODES) offsets[base + 2] = e2;
        }
    }
    if (tid == 255) bsum[blockIdx.x] = wbase + inc;
}

__global__ __launch_bounds__(128) void k_scan2(int* __restrict__ bsum) {
    __shared__ int sh[SCAN_NBLK];
    int tid = threadIdx.x;
    if (tid < SCAN_NBLK) sh[tid] = bsum[tid];
    __syncthreads();
    if (tid == 0) {
        int run = 0;
        for (int i = 0; i < SCAN_NBLK; ++i) { int v = sh[i]; sh[i] = run; run += v; }
    }
    __syncthreads();
    if (tid < SCAN_NBLK) bsum[tid] = sh[tid];
}

__global__ __launch_bounds__(256) void k_scan3(int* __restrict__ offsets,
                                               int* __restrict__ cursor,
                                               const int* __restrict__ bsum) {
    int base = blockIdx.x * SCAN_CHUNK + threadIdx.x * 4;
    int bb = bsum[blockIdx.x];
    if (base + 3 < N_NODES) {
        int4 v = *(const int4*)&offsets[base];
        v.x += bb; v.y += bb; v.z += bb; v.w += bb;
        *(int4*)&offsets[base] = v;
        *(int4*)&cursor[base] = v;
    } else {
        for (int j = 0; j < 4; ++j) {
            int idx = base + j;
            if (idx < N_NODES) { int v = offsets[idx] + bb; offsets[idx] = v; cursor[idx] = v; }
        }
    }
    if (blockIdx.x == 0 && threadIdx.x == 0) offsets[N_NODES] = N_EDGES;
}

// ONE THREAD per edge
__global__ __launch_bounds__(256) void k_msg(
    const int* __restrict__ edges, const float* __restrict__ P,
    const float* __restrict__ hnorm2, const float* __restrict__ rnorm2,
    int* __restrict__ cursor, int4* __restrict__ recs)
{
    int i = blockIdx.x * blockDim.x + threadIdx.x;
    if (i >= N_EDGES) return;
    int rel = edges[i * 6 + 2];
    int sub = edges[i * 6 + 4];
    int obj = edges[i * 6 + 5];

    float pc = P[(size_t)sub * N_REL + rel];
    float ps = hnorm2[sub];
    float pr = rnorm2[rel];

    const float MAXN = 0.996f;
    float ns = fmaxf(sqrtf(ps), 1e-15f);
    float cs = fminf(tanhf(fminf(ns, 15.f)), MAXN);
    float sx = cs / ns;
    float x2 = cs * cs;
    float nr = fmaxf(sqrtf(pr), 1e-15f);
    float cr = fminf(tanhf(fminf(nr, 15.f)), MAXN);
    float sy = cr / nr;
    float y2 = cr * cr;
    float xy = pc * sx * sy;
    float ca = 1.f + 2.f * xy + y2;
    float cb = 1.f - x2;
    float den = fmaxf(1.f + 2.f * xy + x2 * y2, 1e-15f);
    float id = 1.f / den;
    float pm = fmaxf((ca * ca * x2 + 2.f * ca * cb * xy + cb * cb * y2) * id * id, 0.f);
    float nm = fmaxf(sqrtf(pm), 1e-15f);
    float a  = atanhf(fminf(nm, MAXN));
    float sc = a / nm;
    float alpha = sc * id * ca * sx;
    float beta  = sc * id * cb * sy;

    int pos = atomicAdd(&cursor[obj], 1);
    recs[pos] = make_int4(sub, rel, __float_as_int(alpha), __float_as_int(beta));
}

// wave per node: walk sorted records; write A' row bf16 + amp/att
__global__ __launch_bounds__(256) void k_agg(
    const float* __restrict__ hidden, const float* __restrict__ rela,
    const int4* __restrict__ recs, const int* __restrict__ offsets,
    const int* __restrict__ inv, unsigned short* __restrict__ Ap,
    float* __restrict__ amp, float* __restrict__ att)
{
    int node = blockIdx.x * 4 + (threadIdx.x >> 6);
    int lane = threadIdx.x & 63;
    if (node >= N_NODES) return;
    int beg = offsets[node], end = offsets[node + 1];
    float s0 = 0.f, s1 = 0.f, q0 = 0.f, q1 = 0.f;
    float mx0 = -INFINITY, mx1 = -INFINITY, mn0 = INFINITY, mn1 = INFINITY;
    for (int e = beg; e < end; ++e) {
        int4 rc = recs[e];
        float al = __int_as_float(rc.z), be = __int_as_float(rc.w);
        float2 u = *(const float2*)&hidden[rc.x * DIM + lane * 2];
        float2 r = *(const float2*)&rela[rc.y * DIM + lane * 2];
        float m0 = al * u.x + be * r.x;
        float m1 = al * u.y + be * r.y;
        s0 += m0; s1 += m1;
        q0 = fmaf(m0, m0, q0); q1 = fmaf(m1, m1, q1);
        mx0 = fmaxf(mx0, m0); mx1 = fmaxf(mx1, m1);
        mn0 = fminf(mn0, m0); mn1 = fminf(mn1, m1);
    }
    float d  = (float)(end - beg);
    float d1 = fmaxf(d, 1.f);
    float me0 = s0 / d1, me1 = s1 / d1;
    float sd0 = sqrtf(fmaxf(q0 / d1 - me0 * me0, 0.f) + 1e-10f);
    float sd1 = sqrtf(fmaxf(q1 / d1 - me1 * me1, 0.f) + 1e-10f);
    if (!(d > 0.f)) { mx0 = mx1 = mn0 = mn1 = 0.f; }

    unsigned short* row = Ap + (size_t)node * KA;
    int o = lane * 2;
    st_bf2(row +   0 + o, me0, me1);
    st_bf2(row + 128 + o, mx0, mx1);
    st_bf2(row + 256 + o, mn0, mn1);
    st_bf2(row + 384 + o, sd0, sd1);
    int ii = inv[node];
    float h0 = 0.f, h1 = 0.f;
    if (ii >= 0) {
        float2 h = *(const float2*)&hidden[(size_t)ii * DIM + o];
        h0 = h.x; h1 = h.y;
    }
    st_bf2(row + 512 + o, h0, h1);
    if (lane == 0) {
        float logd = log1pf(d);
        amp[node] = logd;
        att[node] = 1.f / fmaxf(logd, 1e-5f);
    }
}

// C[100000][384] = A'[100000][640] @ B'^T[384][640]; fused combine in epilogue
__global__ __launch_bounds__(512) void k_gemm_mfma(
    const unsigned short* __restrict__ Ap,
    const unsigned short* __restrict__ Wt,
    const float* __restrict__ amp, const float* __restrict__ att,
    const float* __restrict__ bias, float* __restrict__ out)
{
    __shared__ uint4 As4[128 * 8];
    __shared__ uint4 Bs4[NB * 8];
    int tid = threadIdx.x;
    int wave = tid >> 6, lane = tid & 63;
    int wm = wave >> 2, wn = wave & 3;
    int l15 = lane & 15, l4 = lane >> 4;
    int m0 = blockIdx.x * 128;

    f32x4 acc[4][6];
#pragma unroll
    for (int mi = 0; mi < 4; ++mi)
#pragma unroll
        for (int nj = 0; nj < 6; ++nj) acc[mi][nj] = (f32x4){0.f, 0.f, 0.f, 0.f};

    for (int k0 = 0; k0 < KA; k0 += 64) {
#pragma unroll
        for (int it = 0; it < 2; ++it) {
            int c = tid + it * 512;
            int row = c >> 3, ko = c & 7;
            int gr = m0 + row; if (gr >= N_NODES) gr = N_NODES - 1;
            As4[row * 8 + (ko ^ (row & 7))] =
                *((const uint4*)(Ap + (size_t)gr * KA + k0) + ko);
        }
#pragma unroll
        for (int it = 0; it < 6; ++it) {
            int c = tid + it * 512;
            int row = c >> 3, ko = c & 7;
            Bs4[row * 8 + (ko ^ (row & 7))] =
                *((const uint4*)(Wt + (size_t)row * KA + k0) + ko);
        }
        __syncthreads();
#pragma unroll
        for (int h = 0; h < 2; ++h) {
            int kc = h * 4 + l4;
            bf16x8 af[4], bfr[6];
#pragma unroll
            for (int mi = 0; mi < 4; ++mi) {
                int r = wm * 64 + mi * 16 + l15;
                uint4 t = As4[r * 8 + (kc ^ (r & 7))];
                af[mi] = *(bf16x8*)&t;
            }
#pragma unroll
            for (int g = 0; g < 3; ++g)
#pragma unroll
                for (int t2 = 0; t2 < 2; ++t2) {
                    int cc = g * 128 + wn * 32 + t2 * 16 + l15;
                    uint4 t = Bs4[cc * 8 + (kc ^ (cc & 7))];
                    bfr[g * 2 + t2] = *(bf16x8*)&t;
                }
#pragma unroll
            for (int mi = 0; mi < 4; ++mi)
#pragma unroll
                for (int nj = 0; nj < 6; ++nj)
                    acc[mi][nj] = __builtin_amdgcn_mfma_f32_16x16x32_bf16(
                        af[mi], bfr[nj], acc[mi][nj], 0, 0, 0);
        }
        __syncthreads();
    }
#pragma unroll
    for (int mi = 0; mi < 4; ++mi) {
#pragma unroll
        for (int rg = 0; rg < 4; ++rg) {
            int row = m0 + wm * 64 + mi * 16 + l4 * 4 + rg;
            if (row >= N_NODES) continue;
            float am = amp[row], at = att[row];
#pragma unroll
            for (int t2 = 0; t2 < 2; ++t2) {
                int c = wn * 32 + t2 * 16 + l15;
                float v = acc[mi][t2][rg] + am * acc[mi][2 + t2][rg]
                        + at * acc[mi][4 + t2][rg] + bias[c];
                out[(size_t)row * DIM + c] = v;
            }
        }
    }
}

__global__ void k_user(const int* __restrict__ user_idx, const float* __restrict__ htilde,
                       float* __restrict__ h_user) {
    int t = blockIdx.x * blockDim.x + threadIdx.x;
    if (t < BATCH * DIM) {
        int b = t >> 7, d = t & 127;
        int idx = user_idx[b];
        if (idx == 0x7FFFFFFF) idx = 0;
        h_user[t] = htilde[(size_t)idx * DIM + d];
    }
}

__global__ __launch_bounds__(256) void k_score(
    const float* __restrict__ h_user, const int* __restrict__ nodes,
    const float* __restrict__ Wsc, const float* __restrict__ bsc,
    float* __restrict__ out)
{
    int wid = (blockIdx.x * blockDim.x + threadIdx.x) >> 6;
    int lane = threadIdx.x & 63;
    if (wid >= N_NODES) return;
    int b = nodes[2 * wid];
    float2 hu = *(const float2*)&h_user[b * DIM + lane * 2];
    float2 ht = *(const float2*)&out[(size_t)wid * DIM + lane * 2];
    float2 w0 = *(const float2*)&Wsc[lane * 2];
    float2 w1 = *(const float2*)&Wsc[DIM + lane * 2];
    float p = hu.x * w0.x + hu.y * w0.y + ht.x * w1.x + ht.y * w1.y;
#pragma unroll
    for (int off = 32; off; off >>= 1) p += __shfl_xor(p, off);
    float alpha = 1.f / (1.f + expf(-(p + bsc[0])));
    float2 o = make_float2(alpha * ht.x, alpha * ht.y);
    *(float2*)&out[(size_t)wid * DIM + lane * 2] = o;
}

extern "C" void kernel_launch(void* const* d_in, const int* in_sizes, int n_in,
                              void* d_out, int out_size, void* d_ws, size_t ws_size,
                              hipStream_t stream)
{
    const float* hidden = (const float*)d_in[0];
    const float* rela   = (const float*)d_in[1];
    const float* W_agg  = (const float*)d_in[2];
    const float* b_agg  = (const float*)d_in[3];
    const float* W_sc   = (const float*)d_in[4];
    const float* b_sc   = (const float*)d_in[5];
    const int* edges    = (const int*)d_in[6];
    const int* nodes    = (const int*)d_in[7];
    const int* q_sub    = (const int*)d_in[8];
    const int* old_idx  = (const int*)d_in[9];
    float* out = (float*)d_out;

    char* p = (char*)d_ws;
    auto carve = [&](size_t bytes) { char* r = p; p += (bytes + 255) & ~255ULL; return r; };
    unsigned short* Ap  = (unsigned short*)carve((size_t)N_NODES * KA * 2);  // 128 MB
    unsigned short* Wtb = (unsigned short*)carve((size_t)NB * KA * 2);
    unsigned short* hB  = (unsigned short*)carve((size_t)N_PREV * DIM * 2);  // 20.5 MB
    unsigned short* rB  = (unsigned short*)carve((size_t)48 * DIM * 2);
    int4*  recs    = (int4*) carve((size_t)N_EDGES * 16);                    // 16 MB
    float* P       = (float*)carve((size_t)N_PREV * N_REL * 4);              // 13.8 MB
    float* hnorm2  = (float*)carve((size_t)N_PREV * 4);
    float* rnorm2  = (float*)carve(N_REL * 4);
    int*   cnt     = (int*)  carve((size_t)N_NODES * 4);
    int*   offsets = (int*)  carve(((size_t)N_NODES + 1) * 4);
    int*   cursor  = (int*)  carve((size_t)N_NODES * 4);
    int*   inv     = (int*)  carve((size_t)N_NODES * 4);
    float* amp     = (float*)carve((size_t)N_NODES * 4);
    float* att     = (float*)carve((size_t)N_NODES * 4);
    int*   bsum    = (int*)  carve(SCAN_NBLK * 4);
    int*   user_idx = (int*) carve(BATCH * 4);
    float* h_user   = (float*)carve(BATCH * DIM * 4);

    k_setup<<<(N_NODES + 255) / 256, 256, 0, stream>>>(cnt, inv, user_idx);
    k_scatter<<<(N_NODES + 255) / 256, 256, 0, stream>>>(old_idx, nodes, q_sub, inv, user_idx);
    k_count<<<(N_EDGES + 255) / 256, 256, 0, stream>>>(edges, cnt);
    k_convW<<<(NB * KA + 255) / 256, 256, 0, stream>>>(W_agg, Wtb);
    k_convH<<<(N_PREV * DIM / 4 + 255) / 256, 256, 0, stream>>>(hidden, hB);
    k_convR<<<(48 * DIM + 255) / 256, 256, 0, stream>>>(rela, rB);
    k_norms<<<(N_PREV + N_REL + 3) / 4, 256, 0, stream>>>(hidden, rela, hnorm2, rnorm2);
    k_dotP<<<N_PREV / 64, 256, 0, stream>>>(hB, rB, P);
    k_scan1<<<SCAN_NBLK, 256, 0, stream>>>(cnt, offsets, bsum);
    k_scan2<<<1, 128, 0, stream>>>(bsum);
    k_scan3<<<SCAN_NBLK, 256, 0, stream>>>(offsets, cursor, bsum);
    k_msg<<<(N_EDGES + 255) / 256, 256, 0, stream>>>(edges, P, hnorm2, rnorm2, cursor, recs);
    k_agg<<<(N_NODES + 3) / 4, 256, 0, stream>>>(hidden, rela, recs, offsets, inv, Ap, amp, att);
    k_gemm_mfma<<<(N_NODES + 127) / 128, 512, 0, stream>>>(Ap, Wtb, amp, att, b_agg, out);
    k_user<<<4, 256, 0, stream>>>(user_idx, out, h_user);
    k_score<<<(N_NODES * 64 + 255) / 256, 256, 0, stream>>>(h_user, nodes, W_sc, b_sc, out);
}